// Round 1
// baseline (2020.502 us; speedup 1.0000x reference)
//
#include <hip/hip_runtime.h>
#include <math.h>

#define B_ 8
#define N_ 1024
#define D_ 384
#define NH_ 8
#define HD_ 48
#define HID2_ 1536
#define HID_ 768
#define M_ (B_*N_)   /* 8192 */

// ---------------- LayerNorm: one wave per row ----------------
__global__ __launch_bounds__(256) void ln_kernel(
    const float* __restrict__ x, const float* __restrict__ g,
    const float* __restrict__ b, float* __restrict__ out) {
    int wave = threadIdx.x >> 6;
    int lane = threadIdx.x & 63;
    int row  = blockIdx.x * 4 + wave;
    const float* xr = x + (size_t)row * D_;
    float vals[6];
    float s = 0.f;
    #pragma unroll
    for (int i = 0; i < 6; ++i) { vals[i] = xr[lane + 64*i]; s += vals[i]; }
    #pragma unroll
    for (int off = 1; off < 64; off <<= 1) s += __shfl_xor(s, off);
    float mean = s * (1.0f/D_);
    float vs = 0.f;
    #pragma unroll
    for (int i = 0; i < 6; ++i) { float t = vals[i]-mean; vs += t*t; }
    #pragma unroll
    for (int off = 1; off < 64; off <<= 1) vs += __shfl_xor(vs, off);
    float rstd = rsqrtf(vs * (1.0f/D_) + 1e-5f);
    float* orow = out + (size_t)row * D_;
    #pragma unroll
    for (int i = 0; i < 6; ++i) {
        int d = lane + 64*i;
        orow[d] = (vals[i]-mean)*rstd*g[d] + b[d];
    }
}

// ---------------- GEMM: out[m][o] = sum_k A[m][k]*W[o][k] + bias[o] (+res) ----
// A: [M,K] row-major.  W: [O,K] row-major (so this computes A @ W^T).
// BM=BO=64, BK=16, 256 threads, 4x4 micro-tile per thread.
template<bool ADD_RES>
__global__ __launch_bounds__(256) void gemm_kernel(
    const float* __restrict__ A, const float* __restrict__ W,
    const float* __restrict__ bias, const float* __restrict__ res,
    float* __restrict__ out, int M, int O, int K) {
    // 68-wide rows: 272B = 16B-aligned rows, and 2-way-max bank aliasing
    __shared__ float As[16][68];
    __shared__ float Ws[16][68];
    int tid = threadIdx.x;
    int tx = tid & 15, ty = tid >> 4;
    int o0 = blockIdx.x * 64;
    int m0 = blockIdx.y * 64;
    int r = tid >> 2, kq = tid & 3;
    float acc[4][4] = {};
    for (int k0 = 0; k0 < K; k0 += 16) {
        float4 av = *(const float4*)(A + (size_t)(m0+r)*K + k0 + kq*4);
        float4 wv = *(const float4*)(W + (size_t)(o0+r)*K + k0 + kq*4);
        __syncthreads();  // previous iteration's LDS reads done
        As[kq*4+0][r]=av.x; As[kq*4+1][r]=av.y; As[kq*4+2][r]=av.z; As[kq*4+3][r]=av.w;
        Ws[kq*4+0][r]=wv.x; Ws[kq*4+1][r]=wv.y; Ws[kq*4+2][r]=wv.z; Ws[kq*4+3][r]=wv.w;
        __syncthreads();
        #pragma unroll
        for (int k = 0; k < 16; ++k) {
            float4 a4 = *(const float4*)(&As[k][ty*4]);
            float4 w4 = *(const float4*)(&Ws[k][tx*4]);
            float aa[4] = {a4.x,a4.y,a4.z,a4.w};
            float ww[4] = {w4.x,w4.y,w4.z,w4.w};
            #pragma unroll
            for (int i=0;i<4;++i)
              #pragma unroll
              for (int j=0;j<4;++j)
                acc[i][j] += aa[i]*ww[j];
        }
    }
    #pragma unroll
    for (int i=0;i<4;++i) {
        int m = m0 + ty*4 + i;
        float vals[4];
        #pragma unroll
        for (int j=0;j<4;++j) {
            int o = o0 + tx*4 + j;
            float v = acc[i][j] + bias[o];
            if (ADD_RES) v += res[(size_t)m*O + o];
            vals[j] = v;
        }
        float4 ov; ov.x=vals[0]; ov.y=vals[1]; ov.z=vals[2]; ov.w=vals[3];
        *(float4*)(out + (size_t)m*O + o0 + tx*4) = ov;
    }
}

// ---------------- Flash attention with spectral decay bias ----------------
// grid: (B*NH, N/QB), 256 threads. QB=32 q-rows, KB=64 k-cols per tile.
// thread t: qr = t>>3 (q-row), lg = t&7; owns 8 k-cols (kc=j*8+lg) for scores
// and 6 output dims (d = lg*6..lg*6+5) for the PV accumulation.
#define QB 32
#define KB 64
__global__ __launch_bounds__(256) void attn_kernel(
    const float* __restrict__ qkv, float* __restrict__ out) {
    __shared__ float q_s[QB][49];
    __shared__ float k_s[KB][49];
    __shared__ float v_s[KB][49];
    __shared__ float p_s[QB][65];
    int bh = blockIdx.x;
    int b = bh >> 3, h = bh & 7;
    int q0 = blockIdx.y * QB;
    int tid = threadIdx.x;
    float decay = logf(1.0f - exp2f(-2.0f - 0.5f*(float)h));  // negative
    const float scale = 0.14433756729740643f;                 // 48^-0.5
    const float* base = qkv + (size_t)b*N_*(3*D_) + h*HD_;
    for (int idx = tid; idx < QB*HD_; idx += 256) {
        int qr = idx / HD_, d = idx % HD_;
        q_s[qr][d] = base[(size_t)(q0+qr)*(3*D_) + d] * scale;
    }
    int qr = tid >> 3;
    int lg = tid & 7;
    int d0 = lg * 6;
    float m_i = -1e30f, l_i = 0.f;
    float o_acc[6] = {};
    __syncthreads();
    for (int kt = 0; kt < N_/KB; ++kt) {
        int n0 = kt * KB;
        for (int idx = tid; idx < KB*HD_; idx += 256) {
            int kc = idx / HD_, d = idx % HD_;
            k_s[kc][d] = base[(size_t)(n0+kc)*(3*D_) + D_   + d];
            v_s[kc][d] = base[(size_t)(n0+kc)*(3*D_) + 2*D_ + d];
        }
        __syncthreads();
        float s[8];
        #pragma unroll
        for (int j=0;j<8;++j) s[j] = 0.f;
        for (int d = 0; d < HD_; ++d) {
            float qv = q_s[qr][d];
            #pragma unroll
            for (int j=0;j<8;++j) s[j] += qv * k_s[j*8+lg][d];
        }
        #pragma unroll
        for (int j=0;j<8;++j) {
            int kc = n0 + j*8 + lg;
            s[j] += fabsf((float)(q0+qr) - (float)kc) * decay;
        }
        float mt = s[0];
        #pragma unroll
        for (int j=1;j<8;++j) mt = fmaxf(mt, s[j]);
        mt = fmaxf(mt, __shfl_xor(mt,1));
        mt = fmaxf(mt, __shfl_xor(mt,2));
        mt = fmaxf(mt, __shfl_xor(mt,4));
        float m_new = fmaxf(m_i, mt);
        float alpha = __expf(m_i - m_new);
        float ps = 0.f;
        #pragma unroll
        for (int j=0;j<8;++j) { s[j] = __expf(s[j]-m_new); ps += s[j]; }
        ps += __shfl_xor(ps,1); ps += __shfl_xor(ps,2); ps += __shfl_xor(ps,4);
        l_i = l_i*alpha + ps;
        m_i = m_new;
        #pragma unroll
        for (int dd=0;dd<6;++dd) o_acc[dd] *= alpha;
        #pragma unroll
        for (int j=0;j<8;++j) p_s[qr][j*8+lg] = s[j];
        __syncthreads();
        #pragma unroll 8
        for (int kc=0;kc<KB;++kc) {
            float pv = p_s[qr][kc];
            #pragma unroll
            for (int dd=0;dd<6;++dd) o_acc[dd] += pv * v_s[kc][d0+dd];
        }
        __syncthreads();
    }
    float inv_l = 1.0f / l_i;
    float* orow = out + (size_t)(b*N_ + q0 + qr)*D_ + h*HD_ + d0;
    #pragma unroll
    for (int dd=0;dd<6;++dd) orow[dd] = o_acc[dd]*inv_l;
}

// ---------------- Depthwise 3x3 conv + GELU gate ----------------
// h: [(b*N + n)][1536]  (channel-fastest => fully coalesced across lanes)
// g: [(b*N + n)][768]   g[c] = gelu(dw(h[:,c])) * dw(h[:,c+768])
__global__ __launch_bounds__(256) void dwconv_gate_kernel(
    const float* __restrict__ h, const float* __restrict__ dw_w,
    const float* __restrict__ dw_b, float* __restrict__ g) {
    int c = blockIdx.x * 256 + threadIdx.x;   // 0..767
    int n = blockIdx.y;
    int b = blockIdx.z;
    int y = n >> 5, x = n & 31;
    const float* hb = h + (size_t)b*N_*HID2_;
    float acc1 = dw_b[c], acc2 = dw_b[c+HID_];
    const float* w1 = dw_w + (size_t)c*9;
    const float* w2 = dw_w + (size_t)(c+HID_)*9;
    #pragma unroll
    for (int ky=0; ky<3; ++ky) {
        int yy = y + ky - 1;
        if (yy < 0 || yy >= 32) continue;
        #pragma unroll
        for (int kx=0; kx<3; ++kx) {
            int xx = x + kx - 1;
            if (xx < 0 || xx >= 32) continue;
            int nn = yy*32 + xx;
            acc1 += hb[(size_t)nn*HID2_ + c]       * w1[ky*3+kx];
            acc2 += hb[(size_t)nn*HID2_ + c+HID_]  * w2[ky*3+kx];
        }
    }
    float ge = 0.5f*acc1*(1.0f + erff(acc1*0.70710678118f));
    g[(size_t)(b*N_ + n)*HID_ + c] = ge * acc2;
}

extern "C" void kernel_launch(void* const* d_in, const int* in_sizes, int n_in,
                              void* d_out, int out_size, void* d_ws, size_t ws_size,
                              hipStream_t stream) {
    const float* x_in   = (const float*)d_in[0];
    const float* qkv_w  = (const float*)d_in[1];
    const float* qkv_b  = (const float*)d_in[2];
    const float* proj_w = (const float*)d_in[3];
    const float* proj_b = (const float*)d_in[4];
    const float* ln1_g  = (const float*)d_in[5];
    const float* ln1_b  = (const float*)d_in[6];
    const float* ln2_g  = (const float*)d_in[7];
    const float* ln2_b  = (const float*)d_in[8];
    const float* pin_w  = (const float*)d_in[9];
    const float* pin_b  = (const float*)d_in[10];
    const float* dw_w   = (const float*)d_in[11];
    const float* dw_b   = (const float*)d_in[12];
    const float* pout_w = (const float*)d_in[13];
    const float* pout_b = (const float*)d_in[14];

    float* pX  = (float*)d_out;                 // persistent activation [M][D]
    float* ws  = (float*)d_ws;
    float* pXn  = ws;                           // [M][D]      LN output
    float* pQKV = pXn + (size_t)M_*D_;          // [M][3D]     (aliased: g [M][HID])
    float* pH   = pQKV + (size_t)M_*3*D_;       // [M][HID2]   (aliased: attn-out [M][D])
    float* pAO  = pH;
    float* pG   = pQKV;
    // ws bytes needed: (M*D + M*3D + M*HID2)*4 = 100.7 MB

    hipMemcpyAsync(pX, x_in, sizeof(float)*(size_t)M_*D_,
                   hipMemcpyDeviceToDevice, stream);

    for (int l = 0; l < 2; ++l) {
        ln_kernel<<<M_/4, 256, 0, stream>>>(pX, ln1_g + l*D_, ln1_b + l*D_, pXn);
        gemm_kernel<false><<<dim3((3*D_)/64, M_/64), 256, 0, stream>>>(
            pXn, qkv_w + (size_t)l*3*D_*D_, qkv_b + (size_t)l*3*D_,
            nullptr, pQKV, M_, 3*D_, D_);
        attn_kernel<<<dim3(B_*NH_, N_/QB), 256, 0, stream>>>(pQKV, pAO);
        gemm_kernel<true><<<dim3(D_/64, M_/64), 256, 0, stream>>>(
            pAO, proj_w + (size_t)l*D_*D_, proj_b + (size_t)l*D_,
            pX, pX, M_, D_, D_);
        ln_kernel<<<M_/4, 256, 0, stream>>>(pX, ln2_g + l*D_, ln2_b + l*D_, pXn);
        gemm_kernel<false><<<dim3(HID2_/64, M_/64), 256, 0, stream>>>(
            pXn, pin_w + (size_t)l*HID2_*D_, pin_b + (size_t)l*HID2_,
            nullptr, pH, M_, HID2_, D_);
        dwconv_gate_kernel<<<dim3(HID_/256, N_, B_), 256, 0, stream>>>(
            pH, dw_w + (size_t)l*HID2_*9, dw_b + (size_t)l*HID2_, pG);
        gemm_kernel<true><<<dim3(D_/64, M_/64), 256, 0, stream>>>(
            pG, pout_w + (size_t)l*D_*HID_, pout_b + (size_t)l*D_,
            pX, pX, M_, D_, HID_);
    }
}

// Round 2
// 561.194 us; speedup vs baseline: 3.6004x; 3.6004x over previous
//
#include <hip/hip_runtime.h>
#include <math.h>

#define B_ 8
#define N_ 1024
#define D_ 384
#define NH_ 8
#define HD_ 48
#define HID2_ 1536
#define HID_ 768
#define M_ (B_*N_)   /* 8192 */

typedef __attribute__((ext_vector_type(4))) float f32x4;
typedef __attribute__((ext_vector_type(8))) short bf16x8;  // 8 bf16 raw bits

__device__ inline unsigned short f2bf(float f) {
    unsigned u = __builtin_bit_cast(unsigned, f);
    u += 0x7fff + ((u >> 16) & 1);        // RNE
    return (unsigned short)(u >> 16);
}
__device__ inline float bf2f(unsigned short h) {
    unsigned u = ((unsigned)h) << 16;
    return __builtin_bit_cast(float, u);
}

// ---------------- fp32 -> bf16 convert ----------------
__global__ __launch_bounds__(256) void cvt_kernel(
    const float* __restrict__ in, unsigned short* __restrict__ out, int n) {
    int i = blockIdx.x * 256 + threadIdx.x;
    if (i < n) out[i] = f2bf(in[i]);
}

// ---------------- LayerNorm: one wave per row, bf16 out ----------------
__global__ __launch_bounds__(256) void ln_kernel(
    const float* __restrict__ x, const float* __restrict__ g,
    const float* __restrict__ b, unsigned short* __restrict__ out) {
    int wave = threadIdx.x >> 6;
    int lane = threadIdx.x & 63;
    int row  = blockIdx.x * 4 + wave;
    const float* xr = x + (size_t)row * D_;
    float vals[6];
    float s = 0.f;
    #pragma unroll
    for (int i = 0; i < 6; ++i) { vals[i] = xr[lane + 64*i]; s += vals[i]; }
    #pragma unroll
    for (int off = 1; off < 64; off <<= 1) s += __shfl_xor(s, off);
    float mean = s * (1.0f/D_);
    float vs = 0.f;
    #pragma unroll
    for (int i = 0; i < 6; ++i) { float t = vals[i]-mean; vs += t*t; }
    #pragma unroll
    for (int off = 1; off < 64; off <<= 1) vs += __shfl_xor(vs, off);
    float rstd = rsqrtf(vs * (1.0f/D_) + 1e-5f);
    unsigned short* orow = out + (size_t)row * D_;
    #pragma unroll
    for (int i = 0; i < 6; ++i) {
        int d = lane + 64*i;
        orow[d] = f2bf((vals[i]-mean)*rstd*g[d] + b[d]);
    }
}

// ---------------- bf16 MFMA GEMM: out[m][o] = A[m][:] . W[o][:] + bias ----
// A: [M,K] bf16 row-major.  W: [O,K] bf16 row-major.  K % 32 == 0.
// 128x128 tile, 256 threads = 4 waves (2x2), each wave 64x64 (4x4 frags).
// MODE 0: bf16 out, no residual.  MODE 1: fp32 out = acc + bias + res.
template<int MODE>
__global__ __launch_bounds__(256) void gemm_bf16(
    const unsigned short* __restrict__ A, const unsigned short* __restrict__ W,
    const float* __restrict__ bias, const float* __restrict__ res,
    void* __restrict__ outv, int M, int O, int K) {
    __shared__ unsigned short a_s[128][40];   // stride 80B -> 2-way banks max
    __shared__ unsigned short w_s[128][40];
    int tid = threadIdx.x;
    int o0 = blockIdx.x * 128;
    int m0 = blockIdx.y * 128;
    int wave = tid >> 6, lane = tid & 63;
    int wm = wave >> 1, wn = wave & 1;
    int lr = lane & 15, lc = lane >> 4;
    int r0 = tid >> 2, ch = tid & 3;     // staging: slot t -> row t>>2, chunk t&3
    int r1 = r0 + 64;                    // slot t+256
    f32x4 acc[4][4];
    #pragma unroll
    for (int i=0;i<4;++i)
      #pragma unroll
      for (int j=0;j<4;++j) acc[i][j] = (f32x4){0.f,0.f,0.f,0.f};

    const unsigned short* pa0 = A + (size_t)(m0+r0)*K + ch*8;
    const unsigned short* pa1 = A + (size_t)(m0+r1)*K + ch*8;
    const unsigned short* pw0 = W + (size_t)(o0+r0)*K + ch*8;
    const unsigned short* pw1 = W + (size_t)(o0+r1)*K + ch*8;
    bf16x8 a0 = *(const bf16x8*)pa0, a1 = *(const bf16x8*)pa1;
    bf16x8 w0 = *(const bf16x8*)pw0, w1 = *(const bf16x8*)pw1;

    for (int k0 = 0; k0 < K; k0 += 32) {
        __syncthreads();
        *(bf16x8*)&a_s[r0][ch*8] = a0;
        *(bf16x8*)&a_s[r1][ch*8] = a1;
        *(bf16x8*)&w_s[r0][ch*8] = w0;
        *(bf16x8*)&w_s[r1][ch*8] = w1;
        __syncthreads();
        if (k0 + 32 < K) {
            pa0 += 32; pa1 += 32; pw0 += 32; pw1 += 32;
            a0 = *(const bf16x8*)pa0; a1 = *(const bf16x8*)pa1;
            w0 = *(const bf16x8*)pw0; w1 = *(const bf16x8*)pw1;
        }
        bf16x8 af[4], wf[4];
        #pragma unroll
        for (int i = 0; i < 4; ++i)
            af[i] = *(const bf16x8*)&a_s[wm*64 + i*16 + lr][lc*8];
        #pragma unroll
        for (int j = 0; j < 4; ++j)
            wf[j] = *(const bf16x8*)&w_s[wn*64 + j*16 + lr][lc*8];
        #pragma unroll
        for (int i = 0; i < 4; ++i)
            #pragma unroll
            for (int j = 0; j < 4; ++j)
                acc[i][j] = __builtin_amdgcn_mfma_f32_16x16x32_bf16(
                    af[i], wf[j], acc[i][j], 0, 0, 0);
    }
    // epilogue: C layout col = lane&15, row = (lane>>4)*4 + reg
    #pragma unroll
    for (int i = 0; i < 4; ++i) {
        int mbase = m0 + wm*64 + i*16 + lc*4;
        #pragma unroll
        for (int j = 0; j < 4; ++j) {
            int oc = o0 + wn*64 + j*16 + lr;
            float bv = bias[oc];
            #pragma unroll
            for (int r = 0; r < 4; ++r) {
                int m = mbase + r;
                float v = acc[i][j][r] + bv;
                if (MODE == 1) {
                    ((float*)outv)[(size_t)m*O + oc] = v + res[(size_t)m*O + oc];
                } else {
                    ((unsigned short*)outv)[(size_t)m*O + oc] = f2bf(v);
                }
            }
        }
    }
}

// ---------------- MFMA flash attention with spectral decay bias ----------
// grid (B*NH, N/64). 256 threads = 4 waves; wave w handles q rows
// [q0 + w*16, q0 + w*16 + 16). KV tiles of 64. Head dim 48 zero-padded to 64.
__global__ __launch_bounds__(256) void attn_mfma(
    const unsigned short* __restrict__ qkv, unsigned short* __restrict__ out) {
    __shared__ unsigned short q_s[64][72];    // [q][hd]  (cols 48..63 zero)
    __shared__ unsigned short k_s[64][72];    // [kv][hd] (cols 48..63 zero)
    __shared__ unsigned short vt_s[48][72];   // [d][kv]  (V transposed)
    __shared__ unsigned short p_s[4][16][72]; // per wave [q][kv]
    int tid = threadIdx.x;
    int wave = tid >> 6, lane = tid & 63;
    int lr = lane & 15, lc = lane >> 4;
    int bh = blockIdx.x;
    int b = bh >> 3, h = bh & 7;
    int q0 = blockIdx.y * 64;
    float decay = logf(1.0f - exp2f(-2.0f - 0.5f*(float)h));  // negative
    const float scale = 0.14433756729740643f;                  // 48^-0.5

    for (int i = tid; i < 64*72; i += 256) {
        ((unsigned short*)q_s)[i] = 0;
        ((unsigned short*)k_s)[i] = 0;
    }
    __syncthreads();
    // stage Q (once)
    const unsigned short* qb = qkv + (size_t)(b*N_ + q0)*1152 + h*48;
    for (int s = tid; s < 384; s += 256) {
        int row = s / 6, c6 = s - row*6;
        *(bf16x8*)&q_s[row][c6*8] = *(const bf16x8*)(qb + (size_t)row*1152 + c6*8);
    }

    f32x4 oacc[3];
    #pragma unroll
    for (int f=0;f<3;++f) oacc[f] = (f32x4){0.f,0.f,0.f,0.f};
    float m_i[4], l_i[4];
    #pragma unroll
    for (int r=0;r<4;++r) { m_i[r] = -3e38f; l_i[r] = 0.f; }

    for (int kt = 0; kt < N_/64; ++kt) {
        int n0 = kt * 64;
        __syncthreads();   // prior tile's k/vt reads done; q_s staged (kt==0)
        const unsigned short* kb = qkv + (size_t)(b*N_ + n0)*1152 + D_ + h*48;
        const unsigned short* vb = kb + D_;
        for (int s = tid; s < 384; s += 256) {
            int row = s / 6, c6 = s - row*6;
            *(bf16x8*)&k_s[row][c6*8] = *(const bf16x8*)(kb + (size_t)row*1152 + c6*8);
            bf16x8 v = *(const bf16x8*)(vb + (size_t)row*1152 + c6*8);
            #pragma unroll
            for (int j = 0; j < 8; ++j) vt_s[c6*8 + j][row] = (unsigned short)v[j];
        }
        __syncthreads();
        // S = Q.K^T  (16 q-rows x 64 keys per wave)
        f32x4 sc[4];
        #pragma unroll
        for (int f=0;f<4;++f) sc[f] = (f32x4){0.f,0.f,0.f,0.f};
        #pragma unroll
        for (int ks = 0; ks < 2; ++ks) {
            bf16x8 aq = *(const bf16x8*)&q_s[wave*16 + lr][ks*32 + lc*8];
            #pragma unroll
            for (int f = 0; f < 4; ++f) {
                bf16x8 bk = *(const bf16x8*)&k_s[f*16 + lr][ks*32 + lc*8];
                sc[f] = __builtin_amdgcn_mfma_f32_16x16x32_bf16(aq, bk, sc[f], 0,0,0);
            }
        }
        // bias + online softmax. S layout: row=(lc*4+r) [q], col=f*16+lr [kv]
        float sf[4][4], mt[4];
        #pragma unroll
        for (int r = 0; r < 4; ++r) {
            float qq = (float)(q0 + wave*16 + lc*4 + r);
            float mm = -3e38f;
            #pragma unroll
            for (int f = 0; f < 4; ++f) {
                float kk = (float)(n0 + f*16 + lr);
                sf[f][r] = sc[f][r]*scale + fabsf(qq - kk)*decay;
                mm = fmaxf(mm, sf[f][r]);
            }
            mt[r] = mm;
        }
        #pragma unroll
        for (int off = 1; off < 16; off <<= 1)
            #pragma unroll
            for (int r = 0; r < 4; ++r)
                mt[r] = fmaxf(mt[r], __shfl_xor(mt[r], off));
        float alpha[4], ps[4];
        #pragma unroll
        for (int r = 0; r < 4; ++r) {
            float mn = fmaxf(m_i[r], mt[r]);
            alpha[r] = __expf(m_i[r] - mn);
            m_i[r] = mn;
            ps[r] = 0.f;
        }
        #pragma unroll
        for (int f = 0; f < 4; ++f)
            #pragma unroll
            for (int r = 0; r < 4; ++r) {
                sf[f][r] = __expf(sf[f][r] - m_i[r]);
                ps[r] += sf[f][r];
            }
        #pragma unroll
        for (int off = 1; off < 16; off <<= 1)
            #pragma unroll
            for (int r = 0; r < 4; ++r)
                ps[r] += __shfl_xor(ps[r], off);
        #pragma unroll
        for (int r = 0; r < 4; ++r) l_i[r] = l_i[r]*alpha[r] + ps[r];
        #pragma unroll
        for (int f = 0; f < 3; ++f)
            #pragma unroll
            for (int r = 0; r < 4; ++r) oacc[f][r] *= alpha[r];
        // P -> LDS (bf16), layout [q][kv]
        #pragma unroll
        for (int f = 0; f < 4; ++f)
            #pragma unroll
            for (int r = 0; r < 4; ++r)
                p_s[wave][lc*4 + r][f*16 + lr] = f2bf(sf[f][r]);
        __syncthreads();
        // O += P.V   A=P: row=q (lane&15), k=kv ; B=V^T from vt_s[d][kv]
        #pragma unroll
        for (int ks = 0; ks < 2; ++ks) {
            bf16x8 ap = *(const bf16x8*)&p_s[wave][lr][ks*32 + lc*8];
            #pragma unroll
            for (int fd = 0; fd < 3; ++fd) {
                bf16x8 bv = *(const bf16x8*)&vt_s[fd*16 + lr][ks*32 + lc*8];
                oacc[fd] = __builtin_amdgcn_mfma_f32_16x16x32_bf16(ap, bv, oacc[fd], 0,0,0);
            }
        }
    }
    #pragma unroll
    for (int fd = 0; fd < 3; ++fd)
        #pragma unroll
        for (int r = 0; r < 4; ++r) {
            int q = q0 + wave*16 + lc*4 + r;
            int d = h*48 + fd*16 + lr;
            out[(size_t)(b*N_ + q)*D_ + d] = f2bf(oacc[fd][r] / l_i[r]);
        }
}

// ---------------- Depthwise 3x3 conv + GELU gate (bf16 io) ----------------
__global__ __launch_bounds__(256) void dwconv_gate_bf16(
    const unsigned short* __restrict__ h, const float* __restrict__ dw_w,
    const float* __restrict__ dw_b, unsigned short* __restrict__ g) {
    int c = blockIdx.x * 256 + threadIdx.x;   // 0..767
    int n = blockIdx.y;
    int b = blockIdx.z;
    int y = n >> 5, x = n & 31;
    const unsigned short* hb = h + (size_t)b*N_*HID2_;
    float acc1 = dw_b[c], acc2 = dw_b[c+HID_];
    const float* w1 = dw_w + (size_t)c*9;
    const float* w2 = dw_w + (size_t)(c+HID_)*9;
    #pragma unroll
    for (int ky=0; ky<3; ++ky) {
        int yy = y + ky - 1;
        if (yy < 0 || yy >= 32) continue;
        #pragma unroll
        for (int kx=0; kx<3; ++kx) {
            int xx = x + kx - 1;
            if (xx < 0 || xx >= 32) continue;
            int nn = yy*32 + xx;
            acc1 += bf2f(hb[(size_t)nn*HID2_ + c])      * w1[ky*3+kx];
            acc2 += bf2f(hb[(size_t)nn*HID2_ + c+HID_]) * w2[ky*3+kx];
        }
    }
    float ge = 0.5f*acc1*(1.0f + erff(acc1*0.70710678118f));
    g[(size_t)(b*N_ + n)*HID_ + c] = f2bf(ge * acc2);
}

extern "C" void kernel_launch(void* const* d_in, const int* in_sizes, int n_in,
                              void* d_out, int out_size, void* d_ws, size_t ws_size,
                              hipStream_t stream) {
    const float* x_in   = (const float*)d_in[0];
    const float* qkv_w  = (const float*)d_in[1];
    const float* qkv_b  = (const float*)d_in[2];
    const float* proj_w = (const float*)d_in[3];
    const float* proj_b = (const float*)d_in[4];
    const float* ln1_g  = (const float*)d_in[5];
    const float* ln1_b  = (const float*)d_in[6];
    const float* ln2_g  = (const float*)d_in[7];
    const float* ln2_b  = (const float*)d_in[8];
    const float* pin_w  = (const float*)d_in[9];
    const float* pin_b  = (const float*)d_in[10];
    const float* dw_w   = (const float*)d_in[11];
    const float* dw_b   = (const float*)d_in[12];
    const float* pout_w = (const float*)d_in[13];
    const float* pout_b = (const float*)d_in[14];

    float* pX = (float*)d_out;                       // residual stream fp32
    unsigned short* wXn  = (unsigned short*)d_ws;                 // [M][384]
    unsigned short* wQKV = wXn  + (size_t)M_*D_;                  // [M][1152]
    unsigned short* wAO  = wQKV + (size_t)M_*3*D_;                // [M][384]
    unsigned short* wH   = wAO  + (size_t)M_*D_;                  // [M][1536]
    unsigned short* wG   = wH   + (size_t)M_*HID2_;               // [M][768]
    unsigned short* wWq  = wG   + (size_t)M_*HID_;                // weights bf16
    unsigned short* wWp  = wWq  + (size_t)2*3*D_*D_;
    unsigned short* wWi  = wWp  + (size_t)2*D_*D_;
    unsigned short* wWo  = wWi  + (size_t)2*HID2_*D_;

    int n1 = 2*3*D_*D_, n2 = 2*D_*D_, n3 = 2*HID2_*D_, n4 = 2*D_*HID_;
    cvt_kernel<<<(n1+255)/256, 256, 0, stream>>>(qkv_w,  wWq, n1);
    cvt_kernel<<<(n2+255)/256, 256, 0, stream>>>(proj_w, wWp, n2);
    cvt_kernel<<<(n3+255)/256, 256, 0, stream>>>(pin_w,  wWi, n3);
    cvt_kernel<<<(n4+255)/256, 256, 0, stream>>>(pout_w, wWo, n4);

    hipMemcpyAsync(pX, x_in, sizeof(float)*(size_t)M_*D_,
                   hipMemcpyDeviceToDevice, stream);

    for (int l = 0; l < 2; ++l) {
        ln_kernel<<<M_/4, 256, 0, stream>>>(pX, ln1_g + l*D_, ln1_b + l*D_, wXn);
        gemm_bf16<0><<<dim3((3*D_)/128, M_/128), 256, 0, stream>>>(
            wXn, wWq + (size_t)l*3*D_*D_, qkv_b + (size_t)l*3*D_,
            nullptr, wQKV, M_, 3*D_, D_);
        attn_mfma<<<dim3(B_*NH_, N_/64), 256, 0, stream>>>(wQKV, wAO);
        gemm_bf16<1><<<dim3(D_/128, M_/128), 256, 0, stream>>>(
            wAO, wWp + (size_t)l*D_*D_, proj_b + (size_t)l*D_,
            pX, pX, M_, D_, D_);
        ln_kernel<<<M_/4, 256, 0, stream>>>(pX, ln2_g + l*D_, ln2_b + l*D_, wXn);
        gemm_bf16<0><<<dim3(HID2_/128, M_/128), 256, 0, stream>>>(
            wXn, wWi + (size_t)l*HID2_*D_, pin_b + (size_t)l*HID2_,
            nullptr, wH, M_, HID2_, D_);
        dwconv_gate_bf16<<<dim3(HID_/256, N_, B_), 256, 0, stream>>>(
            wH, dw_w + (size_t)l*HID2_*9, dw_b + (size_t)l*HID2_, wG);
        gemm_bf16<1><<<dim3(D_/128, M_/128), 256, 0, stream>>>(
            wG, wWo + (size_t)l*D_*HID_, pout_b + (size_t)l*D_,
            pX, pX, M_, D_, HID_);
    }
}

// Round 3
// 366.325 us; speedup vs baseline: 5.5156x; 1.5320x over previous
//
#include <hip/hip_runtime.h>
#include <math.h>

#define B_ 8
#define N_ 1024
#define D_ 384
#define NH_ 8
#define HD_ 48
#define HID2_ 1536
#define HID_ 768
#define M_ (B_*N_)   /* 8192 */

typedef __attribute__((ext_vector_type(4))) float f32x4;
typedef __attribute__((ext_vector_type(2))) float f32x2;
typedef __attribute__((ext_vector_type(8))) short bf16x8;  // 8 bf16 raw bits

__device__ inline unsigned short f2bf(float f) {
    unsigned u = __builtin_bit_cast(unsigned, f);
    u += 0x7fff + ((u >> 16) & 1);        // RNE
    return (unsigned short)(u >> 16);
}
__device__ inline float bf2f(unsigned short h) {
    unsigned u = ((unsigned)h) << 16;
    return __builtin_bit_cast(float, u);
}

// ---------------- fp32 -> bf16 convert (vectorized, n % 4 == 0) -----------
__global__ __launch_bounds__(256) void cvt_kernel(
    const float* __restrict__ in, unsigned short* __restrict__ out, int n4) {
    int i = blockIdx.x * 256 + threadIdx.x;
    if (i < n4) {
        f32x4 v = *(const f32x4*)(in + (size_t)i*4);
        ushort4 o;
        o.x = f2bf(v[0]); o.y = f2bf(v[1]); o.z = f2bf(v[2]); o.w = f2bf(v[3]);
        *(ushort4*)(out + (size_t)i*4) = o;
    }
}

// ---------------- LayerNorm: one wave per row, bf16 out ----------------
__global__ __launch_bounds__(256) void ln_kernel(
    const float* __restrict__ x, const float* __restrict__ g,
    const float* __restrict__ b, unsigned short* __restrict__ out) {
    int wave = threadIdx.x >> 6;
    int lane = threadIdx.x & 63;
    int row  = blockIdx.x * 4 + wave;
    const float* xr = x + (size_t)row * D_;
    f32x2 v[3];
    float s = 0.f;
    #pragma unroll
    for (int i = 0; i < 3; ++i) {
        v[i] = *(const f32x2*)(xr + i*128 + lane*2);
        s += v[i][0] + v[i][1];
    }
    #pragma unroll
    for (int off = 1; off < 64; off <<= 1) s += __shfl_xor(s, off);
    float mean = s * (1.0f/D_);
    float vs = 0.f;
    #pragma unroll
    for (int i = 0; i < 3; ++i) {
        float t0 = v[i][0]-mean, t1 = v[i][1]-mean;
        vs += t0*t0 + t1*t1;
    }
    #pragma unroll
    for (int off = 1; off < 64; off <<= 1) vs += __shfl_xor(vs, off);
    float rstd = rsqrtf(vs * (1.0f/D_) + 1e-5f);
    unsigned short* orow = out + (size_t)row * D_;
    #pragma unroll
    for (int i = 0; i < 3; ++i) {
        int d = i*128 + lane*2;
        ushort2 o;
        o.x = f2bf((v[i][0]-mean)*rstd*g[d]   + b[d]);
        o.y = f2bf((v[i][1]-mean)*rstd*g[d+1] + b[d+1]);
        *(ushort2*)(orow + d) = o;
    }
}

// ---------------- bf16 MFMA GEMM: out[m][o] = A[m][:] . W[o][:] + bias ----
// A: [M,K] bf16 row-major.  W: [O,K] bf16 row-major.  K % 32 == 0.
// 128x128 tile, 256 threads = 4 waves (2x2), each wave 64x64 (4x4 frags).
// MODE 0: bf16 out, no residual.  MODE 1: fp32 out = acc + bias + res.
template<int MODE>
__global__ __launch_bounds__(256) void gemm_bf16(
    const unsigned short* __restrict__ A, const unsigned short* __restrict__ W,
    const float* __restrict__ bias, const float* __restrict__ res,
    void* __restrict__ outv, int M, int O, int K) {
    __shared__ unsigned short a_s[128][40];   // stride 80B -> 2-way banks max
    __shared__ unsigned short w_s[128][40];
    int tid = threadIdx.x;
    int o0 = blockIdx.x * 128;
    int m0 = blockIdx.y * 128;
    int wave = tid >> 6, lane = tid & 63;
    int wm = wave >> 1, wn = wave & 1;
    int lr = lane & 15, lc = lane >> 4;
    int r0 = tid >> 2, ch = tid & 3;     // staging: slot t -> row t>>2, chunk t&3
    int r1 = r0 + 64;                    // slot t+256
    f32x4 acc[4][4];
    #pragma unroll
    for (int i=0;i<4;++i)
      #pragma unroll
      for (int j=0;j<4;++j) acc[i][j] = (f32x4){0.f,0.f,0.f,0.f};

    const unsigned short* pa0 = A + (size_t)(m0+r0)*K + ch*8;
    const unsigned short* pa1 = A + (size_t)(m0+r1)*K + ch*8;
    const unsigned short* pw0 = W + (size_t)(o0+r0)*K + ch*8;
    const unsigned short* pw1 = W + (size_t)(o0+r1)*K + ch*8;
    bf16x8 a0 = *(const bf16x8*)pa0, a1 = *(const bf16x8*)pa1;
    bf16x8 w0 = *(const bf16x8*)pw0, w1 = *(const bf16x8*)pw1;

    for (int k0 = 0; k0 < K; k0 += 32) {
        __syncthreads();
        *(bf16x8*)&a_s[r0][ch*8] = a0;
        *(bf16x8*)&a_s[r1][ch*8] = a1;
        *(bf16x8*)&w_s[r0][ch*8] = w0;
        *(bf16x8*)&w_s[r1][ch*8] = w1;
        __syncthreads();
        if (k0 + 32 < K) {
            pa0 += 32; pa1 += 32; pw0 += 32; pw1 += 32;
            a0 = *(const bf16x8*)pa0; a1 = *(const bf16x8*)pa1;
            w0 = *(const bf16x8*)pw0; w1 = *(const bf16x8*)pw1;
        }
        bf16x8 af[4], wf[4];
        #pragma unroll
        for (int i = 0; i < 4; ++i)
            af[i] = *(const bf16x8*)&a_s[wm*64 + i*16 + lr][lc*8];
        #pragma unroll
        for (int j = 0; j < 4; ++j)
            wf[j] = *(const bf16x8*)&w_s[wn*64 + j*16 + lr][lc*8];
        #pragma unroll
        for (int i = 0; i < 4; ++i)
            #pragma unroll
            for (int j = 0; j < 4; ++j)
                acc[i][j] = __builtin_amdgcn_mfma_f32_16x16x32_bf16(
                    af[i], wf[j], acc[i][j], 0, 0, 0);
    }
    // epilogue: C layout col = lane&15, row = (lane>>4)*4 + reg
    #pragma unroll
    for (int i = 0; i < 4; ++i) {
        int mbase = m0 + wm*64 + i*16 + lc*4;
        #pragma unroll
        for (int j = 0; j < 4; ++j) {
            int oc = o0 + wn*64 + j*16 + lr;
            float bv = bias[oc];
            #pragma unroll
            for (int r = 0; r < 4; ++r) {
                int m = mbase + r;
                float v = acc[i][j][r] + bv;
                if (MODE == 1) {
                    ((float*)outv)[(size_t)m*O + oc] = v + res[(size_t)m*O + oc];
                } else {
                    ((unsigned short*)outv)[(size_t)m*O + oc] = f2bf(v);
                }
            }
        }
    }
}

// ---------------- MFMA flash attention with spectral decay bias ----------
// grid (B*NH, N/64). 256 threads = 4 waves; wave w handles q rows
// [q0 + w*16, q0 + w*16 + 16). KV tiles of 64. Head dim 48 zero-padded to 64.
__global__ __launch_bounds__(256) void attn_mfma(
    const unsigned short* __restrict__ qkv, unsigned short* __restrict__ out) {
    __shared__ unsigned short q_s[64][72];    // [q][hd]  (cols 48..63 zero)
    __shared__ unsigned short k_s[64][72];    // [kv][hd] (cols 48..63 zero)
    __shared__ unsigned short vt_s[48][72];   // [d][kv]  (V transposed)
    __shared__ unsigned short p_s[4][16][72]; // per wave [q][kv]
    int tid = threadIdx.x;
    int wave = tid >> 6, lane = tid & 63;
    int lr = lane & 15, lc = lane >> 4;
    int bh = blockIdx.x;
    int b = bh >> 3, h = bh & 7;
    int q0 = blockIdx.y * 64;
    float decay = logf(1.0f - exp2f(-2.0f - 0.5f*(float)h));  // negative
    const float scale = 0.14433756729740643f;                  // 48^-0.5

    for (int i = tid; i < 64*72; i += 256) {
        ((unsigned short*)q_s)[i] = 0;
        ((unsigned short*)k_s)[i] = 0;
    }
    __syncthreads();
    // stage Q (once)
    const unsigned short* qb = qkv + (size_t)(b*N_ + q0)*1152 + h*48;
    for (int s = tid; s < 384; s += 256) {
        int row = s / 6, c6 = s - row*6;
        *(bf16x8*)&q_s[row][c6*8] = *(const bf16x8*)(qb + (size_t)row*1152 + c6*8);
    }

    f32x4 oacc[3];
    #pragma unroll
    for (int f=0;f<3;++f) oacc[f] = (f32x4){0.f,0.f,0.f,0.f};
    float m_i[4], l_i[4];
    #pragma unroll
    for (int r=0;r<4;++r) { m_i[r] = -3e38f; l_i[r] = 0.f; }

    for (int kt = 0; kt < N_/64; ++kt) {
        int n0 = kt * 64;
        __syncthreads();   // prior tile's k/vt reads done; q_s staged (kt==0)
        const unsigned short* kb = qkv + (size_t)(b*N_ + n0)*1152 + D_ + h*48;
        const unsigned short* vb = kb + D_;
        for (int s = tid; s < 384; s += 256) {
            int row = s / 6, c6 = s - row*6;
            *(bf16x8*)&k_s[row][c6*8] = *(const bf16x8*)(kb + (size_t)row*1152 + c6*8);
            bf16x8 v = *(const bf16x8*)(vb + (size_t)row*1152 + c6*8);
            #pragma unroll
            for (int j = 0; j < 8; ++j) vt_s[c6*8 + j][row] = (unsigned short)v[j];
        }
        __syncthreads();
        // S = Q.K^T  (16 q-rows x 64 keys per wave)
        f32x4 sc[4];
        #pragma unroll
        for (int f=0;f<4;++f) sc[f] = (f32x4){0.f,0.f,0.f,0.f};
        #pragma unroll
        for (int ks = 0; ks < 2; ++ks) {
            bf16x8 aq = *(const bf16x8*)&q_s[wave*16 + lr][ks*32 + lc*8];
            #pragma unroll
            for (int f = 0; f < 4; ++f) {
                bf16x8 bk = *(const bf16x8*)&k_s[f*16 + lr][ks*32 + lc*8];
                sc[f] = __builtin_amdgcn_mfma_f32_16x16x32_bf16(aq, bk, sc[f], 0,0,0);
            }
        }
        // bias + online softmax. S layout: row=(lc*4+r) [q], col=f*16+lr [kv]
        float sf[4][4], mt[4];
        #pragma unroll
        for (int r = 0; r < 4; ++r) {
            float qq = (float)(q0 + wave*16 + lc*4 + r);
            float mm = -3e38f;
            #pragma unroll
            for (int f = 0; f < 4; ++f) {
                float kk = (float)(n0 + f*16 + lr);
                sf[f][r] = sc[f][r]*scale + fabsf(qq - kk)*decay;
                mm = fmaxf(mm, sf[f][r]);
            }
            mt[r] = mm;
        }
        #pragma unroll
        for (int off = 1; off < 16; off <<= 1)
            #pragma unroll
            for (int r = 0; r < 4; ++r)
                mt[r] = fmaxf(mt[r], __shfl_xor(mt[r], off));
        float alpha[4], ps[4];
        #pragma unroll
        for (int r = 0; r < 4; ++r) {
            float mn = fmaxf(m_i[r], mt[r]);
            alpha[r] = __expf(m_i[r] - mn);
            m_i[r] = mn;
            ps[r] = 0.f;
        }
        #pragma unroll
        for (int f = 0; f < 4; ++f)
            #pragma unroll
            for (int r = 0; r < 4; ++r) {
                sf[f][r] = __expf(sf[f][r] - m_i[r]);
                ps[r] += sf[f][r];
            }
        #pragma unroll
        for (int off = 1; off < 16; off <<= 1)
            #pragma unroll
            for (int r = 0; r < 4; ++r)
                ps[r] += __shfl_xor(ps[r], off);
        #pragma unroll
        for (int r = 0; r < 4; ++r) l_i[r] = l_i[r]*alpha[r] + ps[r];
        #pragma unroll
        for (int f = 0; f < 3; ++f)
            #pragma unroll
            for (int r = 0; r < 4; ++r) oacc[f][r] *= alpha[r];
        // P -> LDS (bf16), layout [q][kv]
        #pragma unroll
        for (int f = 0; f < 4; ++f)
            #pragma unroll
            for (int r = 0; r < 4; ++r)
                p_s[wave][lc*4 + r][f*16 + lr] = f2bf(sf[f][r]);
        __syncthreads();
        // O += P.V   A=P: row=q (lane&15), k=kv ; B=V^T from vt_s[d][kv]
        #pragma unroll
        for (int ks = 0; ks < 2; ++ks) {
            bf16x8 ap = *(const bf16x8*)&p_s[wave][lr][ks*32 + lc*8];
            #pragma unroll
            for (int fd = 0; fd < 3; ++fd) {
                bf16x8 bv = *(const bf16x8*)&vt_s[fd*16 + lr][ks*32 + lc*8];
                oacc[fd] = __builtin_amdgcn_mfma_f32_16x16x32_bf16(ap, bv, oacc[fd], 0,0,0);
            }
        }
    }
    #pragma unroll
    for (int fd = 0; fd < 3; ++fd)
        #pragma unroll
        for (int r = 0; r < 4; ++r) {
            int q = q0 + wave*16 + lc*4 + r;
            int d = h*48 + fd*16 + lr;
            out[(size_t)(b*N_ + q)*D_ + d] = f2bf(oacc[fd][r] / l_i[r]);
        }
}

// ---------------- Depthwise 3x3 conv + GELU gate, 8 ch/thread ------------
// grid (12, 32, 8): 64 channels x 32 positions (one image row) per block.
// thread: x = tid>>3 (position in row), 8 channels at c0 = cg0 + (tid&7)*8.
// 18 bf16x8 global loads (288B in flight), weights via LDS f32x4 reads.
__global__ __launch_bounds__(256) void dwconv_gate_bf16(
    const unsigned short* __restrict__ h, const float* __restrict__ dw_w,
    const float* __restrict__ dw_b, unsigned short* __restrict__ g) {
    __shared__ float wt_s[9][128];   // [tap][ch: 0..63 = h1, 64..127 = h2]
    __shared__ float bs_s[128];
    int tid = threadIdx.x;
    int cg0 = blockIdx.x * 64;
    int y   = blockIdx.y;
    int b   = blockIdx.z;
    for (int i = tid; i < 1152; i += 256) {
        int tap = i >> 7, cl = i & 127;
        int gch = (cl < 64) ? (cg0 + cl) : (HID_ + cg0 + (cl - 64));
        wt_s[tap][cl] = dw_w[(size_t)gch*9 + tap];
    }
    if (tid < 128) {
        int gch = (tid < 64) ? (cg0 + tid) : (HID_ + cg0 + (tid - 64));
        bs_s[tid] = dw_b[gch];
    }
    __syncthreads();
    int x  = tid >> 3;
    int co = (tid & 7) * 8;          // local channel offset 0..56
    int c1 = cg0 + co;               // global h1 channel base
    const unsigned short* hb = h + (size_t)b*N_*HID2_;
    float acc1[8], acc2[8];
    #pragma unroll
    for (int j=0;j<8;++j) { acc1[j] = bs_s[co+j]; acc2[j] = bs_s[64+co+j]; }
    #pragma unroll
    for (int ky=0; ky<3; ++ky) {
        int yy = y + ky - 1;
        if (yy < 0 || yy >= 32) continue;
        #pragma unroll
        for (int kx=0; kx<3; ++kx) {
            int xx = x + kx - 1;
            if (xx < 0 || xx >= 32) continue;
            const unsigned short* p = hb + (size_t)(yy*32+xx)*HID2_ + c1;
            bf16x8 d1 = *(const bf16x8*)p;
            bf16x8 d2 = *(const bf16x8*)(p + HID_);
            int t = ky*3 + kx;
            f32x4 w1a = *(const f32x4*)&wt_s[t][co];
            f32x4 w1b = *(const f32x4*)&wt_s[t][co+4];
            f32x4 w2a = *(const f32x4*)&wt_s[t][64+co];
            f32x4 w2b = *(const f32x4*)&wt_s[t][64+co+4];
            #pragma unroll
            for (int j=0;j<4;++j) {
                acc1[j]   += bf2f((unsigned short)d1[j])   * w1a[j];
                acc1[j+4] += bf2f((unsigned short)d1[j+4]) * w1b[j];
                acc2[j]   += bf2f((unsigned short)d2[j])   * w2a[j];
                acc2[j+4] += bf2f((unsigned short)d2[j+4]) * w2b[j];
            }
        }
    }
    bf16x8 o;
    #pragma unroll
    for (int j=0;j<8;++j) {
        float ge = 0.5f*acc1[j]*(1.0f + erff(acc1[j]*0.70710678118f));
        o[j] = (short)f2bf(ge * acc2[j]);
    }
    *(bf16x8*)(g + (size_t)(b*N_ + y*32 + x)*HID_ + c1) = o;
}

extern "C" void kernel_launch(void* const* d_in, const int* in_sizes, int n_in,
                              void* d_out, int out_size, void* d_ws, size_t ws_size,
                              hipStream_t stream) {
    const float* x_in   = (const float*)d_in[0];
    const float* qkv_w  = (const float*)d_in[1];
    const float* qkv_b  = (const float*)d_in[2];
    const float* proj_w = (const float*)d_in[3];
    const float* proj_b = (const float*)d_in[4];
    const float* ln1_g  = (const float*)d_in[5];
    const float* ln1_b  = (const float*)d_in[6];
    const float* ln2_g  = (const float*)d_in[7];
    const float* ln2_b  = (const float*)d_in[8];
    const float* pin_w  = (const float*)d_in[9];
    const float* pin_b  = (const float*)d_in[10];
    const float* dw_w   = (const float*)d_in[11];
    const float* dw_b   = (const float*)d_in[12];
    const float* pout_w = (const float*)d_in[13];
    const float* pout_b = (const float*)d_in[14];

    float* pX = (float*)d_out;                       // residual stream fp32
    unsigned short* wXn  = (unsigned short*)d_ws;                 // [M][384]
    unsigned short* wQKV = wXn  + (size_t)M_*D_;                  // [M][1152]
    unsigned short* wAO  = wQKV + (size_t)M_*3*D_;                // [M][384]
    unsigned short* wH   = wAO  + (size_t)M_*D_;                  // [M][1536]
    unsigned short* wG   = wH   + (size_t)M_*HID2_;               // [M][768]
    unsigned short* wWq  = wG   + (size_t)M_*HID_;                // weights bf16
    unsigned short* wWp  = wWq  + (size_t)2*3*D_*D_;
    unsigned short* wWi  = wWp  + (size_t)2*D_*D_;
    unsigned short* wWo  = wWi  + (size_t)2*HID2_*D_;

    int n1 = 2*3*D_*D_, n2 = 2*D_*D_, n3 = 2*HID2_*D_, n4 = 2*D_*HID_;
    cvt_kernel<<<(n1/4+255)/256, 256, 0, stream>>>(qkv_w,  wWq, n1/4);
    cvt_kernel<<<(n2/4+255)/256, 256, 0, stream>>>(proj_w, wWp, n2/4);
    cvt_kernel<<<(n3/4+255)/256, 256, 0, stream>>>(pin_w,  wWi, n3/4);
    cvt_kernel<<<(n4/4+255)/256, 256, 0, stream>>>(pout_w, wWo, n4/4);

    hipMemcpyAsync(pX, x_in, sizeof(float)*(size_t)M_*D_,
                   hipMemcpyDeviceToDevice, stream);

    for (int l = 0; l < 2; ++l) {
        ln_kernel<<<M_/4, 256, 0, stream>>>(pX, ln1_g + l*D_, ln1_b + l*D_, wXn);
        gemm_bf16<0><<<dim3((3*D_)/128, M_/128), 256, 0, stream>>>(
            wXn, wWq + (size_t)l*3*D_*D_, qkv_b + (size_t)l*3*D_,
            nullptr, wQKV, M_, 3*D_, D_);
        attn_mfma<<<dim3(B_*NH_, N_/64), 256, 0, stream>>>(wQKV, wAO);
        gemm_bf16<1><<<dim3(D_/128, M_/128), 256, 0, stream>>>(
            wAO, wWp + (size_t)l*D_*D_, proj_b + (size_t)l*D_,
            pX, pX, M_, D_, D_);
        ln_kernel<<<M_/4, 256, 0, stream>>>(pX, ln2_g + l*D_, ln2_b + l*D_, wXn);
        gemm_bf16<0><<<dim3(HID2_/128, M_/128), 256, 0, stream>>>(
            wXn, wWi + (size_t)l*HID2_*D_, pin_b + (size_t)l*HID2_,
            nullptr, wH, M_, HID2_, D_);
        dwconv_gate_bf16<<<dim3(HID_/64, 32, B_), 256, 0, stream>>>(
            wH, dw_w + (size_t)l*HID2_*9, dw_b + (size_t)l*HID2_, wG);
        gemm_bf16<1><<<dim3(D_/128, M_/128), 256, 0, stream>>>(
            wG, wWo + (size_t)l*D_*HID_, pout_b + (size_t)l*D_,
            pX, pX, M_, D_, HID_);
    }
}

// Round 4
// 334.743 us; speedup vs baseline: 6.0360x; 1.0943x over previous
//
#include <hip/hip_runtime.h>
#include <math.h>

#define B_ 8
#define N_ 1024
#define D_ 384
#define NH_ 8
#define HD_ 48
#define HID2_ 1536
#define HID_ 768
#define M_ (B_*N_)   /* 8192 */

typedef __attribute__((ext_vector_type(4))) float f32x4;
typedef __attribute__((ext_vector_type(2))) float f32x2;
typedef __attribute__((ext_vector_type(8))) short bf16x8;  // 8 bf16 raw bits
typedef __attribute__((ext_vector_type(4))) short bf16x4;  // 4 bf16 raw bits
typedef __attribute__((ext_vector_type(2))) unsigned u32x2;
typedef __attribute__((ext_vector_type(4))) unsigned u32x4;

__device__ inline unsigned short f2bf(float f) {
    unsigned u = __builtin_bit_cast(unsigned, f);
    u += 0x7fff + ((u >> 16) & 1);        // RNE
    return (unsigned short)(u >> 16);
}
__device__ inline float bf2f(unsigned short h) {
    unsigned u = ((unsigned)h) << 16;
    return __builtin_bit_cast(float, u);
}
__device__ inline unsigned cvtpk_bf16(float lo, float hi) {
    unsigned r;
    asm("v_cvt_pk_bf16_f32 %0, %1, %2" : "=v"(r) : "v"(lo), "v"(hi));
    return r;
}
__device__ inline f32x4 mfma16(bf16x4 a, bf16x4 b, f32x4 c) {
#if __has_builtin(__builtin_amdgcn_mfma_f32_16x16x16bf16_1k)
    return __builtin_amdgcn_mfma_f32_16x16x16bf16_1k(a, b, c, 0, 0, 0);
#else
    asm("v_mfma_f32_16x16x16_bf16 %0, %1, %2, %0" : "+v"(c) : "v"(a), "v"(b));
    return c;
#endif
}

// ---------------- fp32 -> bf16 convert (vectorized, n % 4 == 0) -----------
__global__ __launch_bounds__(256) void cvt_kernel(
    const float* __restrict__ in, unsigned short* __restrict__ out, int n4) {
    int i = blockIdx.x * 256 + threadIdx.x;
    if (i < n4) {
        f32x4 v = *(const f32x4*)(in + (size_t)i*4);
        ushort4 o;
        o.x = f2bf(v[0]); o.y = f2bf(v[1]); o.z = f2bf(v[2]); o.w = f2bf(v[3]);
        *(ushort4*)(out + (size_t)i*4) = o;
    }
}

// ---------------- LayerNorm: one wave per row, bf16 out ----------------
__global__ __launch_bounds__(256) void ln_kernel(
    const float* __restrict__ x, const float* __restrict__ g,
    const float* __restrict__ b, unsigned short* __restrict__ out) {
    int wave = threadIdx.x >> 6;
    int lane = threadIdx.x & 63;
    int row  = blockIdx.x * 4 + wave;
    const float* xr = x + (size_t)row * D_;
    f32x2 v[3];
    float s = 0.f;
    #pragma unroll
    for (int i = 0; i < 3; ++i) {
        v[i] = *(const f32x2*)(xr + i*128 + lane*2);
        s += v[i][0] + v[i][1];
    }
    #pragma unroll
    for (int off = 1; off < 64; off <<= 1) s += __shfl_xor(s, off);
    float mean = s * (1.0f/D_);
    float vs = 0.f;
    #pragma unroll
    for (int i = 0; i < 3; ++i) {
        float t0 = v[i][0]-mean, t1 = v[i][1]-mean;
        vs += t0*t0 + t1*t1;
    }
    #pragma unroll
    for (int off = 1; off < 64; off <<= 1) vs += __shfl_xor(vs, off);
    float rstd = rsqrtf(vs * (1.0f/D_) + 1e-5f);
    unsigned short* orow = out + (size_t)row * D_;
    #pragma unroll
    for (int i = 0; i < 3; ++i) {
        int d = i*128 + lane*2;
        ushort2 o;
        o.x = f2bf((v[i][0]-mean)*rstd*g[d]   + b[d]);
        o.y = f2bf((v[i][1]-mean)*rstd*g[d+1] + b[d+1]);
        *(ushort2*)(orow + d) = o;
    }
}

// ---------------- bf16 MFMA GEMM: out[m][o] = A[m][:] . W[o][:] + bias ----
template<int MODE>
__global__ __launch_bounds__(256) void gemm_bf16(
    const unsigned short* __restrict__ A, const unsigned short* __restrict__ W,
    const float* __restrict__ bias, const float* __restrict__ res,
    void* __restrict__ outv, int M, int O, int K) {
    __shared__ unsigned short a_s[128][40];   // stride 80B -> 2-way banks max
    __shared__ unsigned short w_s[128][40];
    int tid = threadIdx.x;
    int o0 = blockIdx.x * 128;
    int m0 = blockIdx.y * 128;
    int wave = tid >> 6, lane = tid & 63;
    int wm = wave >> 1, wn = wave & 1;
    int lr = lane & 15, lc = lane >> 4;
    int r0 = tid >> 2, ch = tid & 3;
    int r1 = r0 + 64;
    f32x4 acc[4][4];
    #pragma unroll
    for (int i=0;i<4;++i)
      #pragma unroll
      for (int j=0;j<4;++j) acc[i][j] = (f32x4){0.f,0.f,0.f,0.f};

    const unsigned short* pa0 = A + (size_t)(m0+r0)*K + ch*8;
    const unsigned short* pa1 = A + (size_t)(m0+r1)*K + ch*8;
    const unsigned short* pw0 = W + (size_t)(o0+r0)*K + ch*8;
    const unsigned short* pw1 = W + (size_t)(o0+r1)*K + ch*8;
    bf16x8 a0 = *(const bf16x8*)pa0, a1 = *(const bf16x8*)pa1;
    bf16x8 w0 = *(const bf16x8*)pw0, w1 = *(const bf16x8*)pw1;

    for (int k0 = 0; k0 < K; k0 += 32) {
        __syncthreads();
        *(bf16x8*)&a_s[r0][ch*8] = a0;
        *(bf16x8*)&a_s[r1][ch*8] = a1;
        *(bf16x8*)&w_s[r0][ch*8] = w0;
        *(bf16x8*)&w_s[r1][ch*8] = w1;
        __syncthreads();
        if (k0 + 32 < K) {
            pa0 += 32; pa1 += 32; pw0 += 32; pw1 += 32;
            a0 = *(const bf16x8*)pa0; a1 = *(const bf16x8*)pa1;
            w0 = *(const bf16x8*)pw0; w1 = *(const bf16x8*)pw1;
        }
        bf16x8 af[4], wf[4];
        #pragma unroll
        for (int i = 0; i < 4; ++i)
            af[i] = *(const bf16x8*)&a_s[wm*64 + i*16 + lr][lc*8];
        #pragma unroll
        for (int j = 0; j < 4; ++j)
            wf[j] = *(const bf16x8*)&w_s[wn*64 + j*16 + lr][lc*8];
        #pragma unroll
        for (int i = 0; i < 4; ++i)
            #pragma unroll
            for (int j = 0; j < 4; ++j)
                acc[i][j] = __builtin_amdgcn_mfma_f32_16x16x32_bf16(
                    af[i], wf[j], acc[i][j], 0, 0, 0);
    }
    #pragma unroll
    for (int i = 0; i < 4; ++i) {
        int mbase = m0 + wm*64 + i*16 + lc*4;
        #pragma unroll
        for (int j = 0; j < 4; ++j) {
            int oc = o0 + wn*64 + j*16 + lr;
            float bv = bias[oc];
            #pragma unroll
            for (int r = 0; r < 4; ++r) {
                int m = mbase + r;
                float v = acc[i][j][r] + bv;
                if (MODE == 1) {
                    ((float*)outv)[(size_t)m*O + oc] = v + res[(size_t)m*O + oc];
                } else {
                    ((unsigned short*)outv)[(size_t)m*O + oc] = f2bf(v);
                }
            }
        }
    }
}

// ---------------- Flash attention, swapped-operand MFMA -------------------
// grid (B*NH, N/64), 256 thr = 4 waves; wave w owns q rows q0+w*16..+15.
// S^T = mfma(K, Q): lane(lr,lc) holds S^T[kv=f*16+lc*4+r][q=lr] -> softmax is
// register-local + 2 shfl. exp'd S^T IS the B-frag of mfma 16x16x16 -> PV
// (O^T = mfma(V^T, P)) needs no P movement. K/Q read direct from global (L2).
// Only V^T staged in LDS (6.9 KB), conflict-free d-owner pattern.
__global__ __launch_bounds__(256) void attn_mfma(
    const unsigned short* __restrict__ qkv, unsigned short* __restrict__ out) {
    __shared__ unsigned short vt_s[48][72];   // [d][kv], 144B row stride
    int tid = threadIdx.x;
    int wave = tid >> 6, lane = tid & 63;
    int lr = lane & 15, lc = lane >> 4;
    int b = blockIdx.x >> 3, h = blockIdx.x & 7;
    int q0 = blockIdx.y * 64;
    const float LOG2E = 1.4426950408889634f;
    float decay = logf(1.0f - exp2f(-2.0f - 0.5f*(float)h)) * LOG2E; // <0
    const float scale2 = 0.14433756729740643f * LOG2E;

    int q = q0 + wave*16 + lr;
    float qqf = (float)q;
    const bf16x8 zero8 = {0,0,0,0,0,0,0,0};

    // Q B-fragments (held in regs for whole kernel); d>=48 zero-padded
    const unsigned short* qrow = qkv + ((size_t)b*N_ + q)*1152 + h*48;
    bf16x8 qf0 = *(const bf16x8*)(qrow + lc*8);
    bf16x8 qf1 = zero8;
    if (lc < 2) qf1 = *(const bf16x8*)(qrow + 32 + lc*8);

    // V^T staging: thread (tid<192) owns d-pair (vd2, vd2+1) x kv-chunk vch
    int vd2 = (tid % 24) * 2;
    int vch = tid / 24;
    bool vact = tid < 192;

    const unsigned short* kbase = qkv + (size_t)b*N_*1152 + D_ + h*48;
    const unsigned short* vbase = kbase + D_;

    float m_i = -3e38f, l_i = 0.f;
    f32x4 oacc[3];
    #pragma unroll
    for (int i=0;i<3;++i) oacc[i] = (f32x4){0.f,0.f,0.f,0.f};

    for (int kt = 0; kt < 16; ++kt) {
        int n0 = kt * 64;
        // issue V loads early (hide under QK+softmax)
        unsigned vv[8];
        if (vact) {
            const unsigned short* vp = vbase + (size_t)(n0 + vch*8)*1152 + vd2;
            #pragma unroll
            for (int i = 0; i < 8; ++i)
                vv[i] = *(const unsigned*)(vp + (size_t)i*1152);
        }
        // S^T = K . Q^T : sc[f][r] = score(q=lr, k=n0+f*16+lc*4+r)
        f32x4 sc[4];
        #pragma unroll
        for (int f = 0; f < 4; ++f) {
            sc[f] = (f32x4){0.f,0.f,0.f,0.f};
            const unsigned short* kp = kbase + (size_t)(n0 + f*16 + lr)*1152;
            bf16x8 kf0 = *(const bf16x8*)(kp + lc*8);
            bf16x8 kf1 = zero8;
            if (lc < 2) kf1 = *(const bf16x8*)(kp + 32 + lc*8);
            sc[f] = __builtin_amdgcn_mfma_f32_16x16x32_bf16(kf0, qf0, sc[f],0,0,0);
            sc[f] = __builtin_amdgcn_mfma_f32_16x16x32_bf16(kf1, qf1, sc[f],0,0,0);
        }
        // bias + max (all in log2 domain)
        float s2[4][4];
        float kv0 = (float)(n0 + lc*4);
        float mt = -3e38f;
        #pragma unroll
        for (int f = 0; f < 4; ++f)
            #pragma unroll
            for (int r = 0; r < 4; ++r) {
                float kk = kv0 + (float)(f*16 + r);
                s2[f][r] = sc[f][r]*scale2 + fabsf(qqf - kk)*decay;
                mt = fmaxf(mt, s2[f][r]);
            }
        mt = fmaxf(mt, __shfl_xor(mt, 16));
        mt = fmaxf(mt, __shfl_xor(mt, 32));
        float mn = fmaxf(m_i, mt);
        float alpha = __builtin_amdgcn_exp2f(m_i - mn);
        m_i = mn;
        float ps = 0.f;
        #pragma unroll
        for (int f = 0; f < 4; ++f)
            #pragma unroll
            for (int r = 0; r < 4; ++r) {
                s2[f][r] = __builtin_amdgcn_exp2f(s2[f][r] - mn);
                ps += s2[f][r];
            }
        ps += __shfl_xor(ps, 16);
        ps += __shfl_xor(ps, 32);
        l_i = l_i*alpha + ps;
        #pragma unroll
        for (int md = 0; md < 3; ++md)
            #pragma unroll
            for (int r = 0; r < 4; ++r) oacc[md][r] *= alpha;
        // P fragments: lane's own 16 values, packed to bf16 pairs (T12)
        bf16x4 pfrag[4];
        #pragma unroll
        for (int f = 0; f < 4; ++f) {
            u32x2 u;
            u[0] = cvtpk_bf16(s2[f][0], s2[f][1]);
            u[1] = cvtpk_bf16(s2[f][2], s2[f][3]);
            pfrag[f] = __builtin_bit_cast(bf16x4, u);
        }
        // stage V^T (conflict-free b128 writes)
        __syncthreads();   // prev PV reads done
        if (vact) {
            u32x4 wlo, whi;
            #pragma unroll
            for (int i = 0; i < 4; ++i) {
                wlo[i] = (vv[2*i] & 0xffffu) | (vv[2*i+1] << 16);
                whi[i] = (vv[2*i] >> 16)    | (vv[2*i+1] & 0xffff0000u);
            }
            *(bf16x8*)&vt_s[vd2]  [vch*8] = __builtin_bit_cast(bf16x8, wlo);
            *(bf16x8*)&vt_s[vd2+1][vch*8] = __builtin_bit_cast(bf16x8, whi);
        }
        __syncthreads();
        // O^T += V^T . P^T  (A = V^T[d][kv] b64 reads, B = pfrag)
        #pragma unroll
        for (int f = 0; f < 4; ++f)
            #pragma unroll
            for (int md = 0; md < 3; ++md) {
                bf16x4 va = *(const bf16x4*)&vt_s[md*16 + lr][f*16 + lc*4];
                oacc[md] = mfma16(va, pfrag[f], oacc[md]);
            }
    }
    float inv_l = 1.0f / l_i;
    #pragma unroll
    for (int md = 0; md < 3; ++md) {
        ushort4 o;
        o.x = f2bf(oacc[md][0]*inv_l);
        o.y = f2bf(oacc[md][1]*inv_l);
        o.z = f2bf(oacc[md][2]*inv_l);
        o.w = f2bf(oacc[md][3]*inv_l);
        *(ushort4*)(out + ((size_t)b*N_ + q)*D_ + h*48 + md*16 + lc*4) = o;
    }
}

// ---------------- Depthwise 3x3 conv + GELU gate, 8 ch/thread ------------
__global__ __launch_bounds__(256) void dwconv_gate_bf16(
    const unsigned short* __restrict__ h, const float* __restrict__ dw_w,
    const float* __restrict__ dw_b, unsigned short* __restrict__ g) {
    __shared__ float wt_s[9][128];   // [tap][ch: 0..63 = h1, 64..127 = h2]
    __shared__ float bs_s[128];
    int tid = threadIdx.x;
    int cg0 = blockIdx.x * 64;
    int y   = blockIdx.y;
    int b   = blockIdx.z;
    for (int i = tid; i < 1152; i += 256) {
        int tap = i >> 7, cl = i & 127;
        int gch = (cl < 64) ? (cg0 + cl) : (HID_ + cg0 + (cl - 64));
        wt_s[tap][cl] = dw_w[(size_t)gch*9 + tap];
    }
    if (tid < 128) {
        int gch = (tid < 64) ? (cg0 + tid) : (HID_ + cg0 + (tid - 64));
        bs_s[tid] = dw_b[gch];
    }
    __syncthreads();
    int x  = tid >> 3;
    int co = (tid & 7) * 8;
    int c1 = cg0 + co;
    const unsigned short* hb = h + (size_t)b*N_*HID2_;
    float acc1[8], acc2[8];
    #pragma unroll
    for (int j=0;j<8;++j) { acc1[j] = bs_s[co+j]; acc2[j] = bs_s[64+co+j]; }
    #pragma unroll
    for (int ky=0; ky<3; ++ky) {
        int yy = y + ky - 1;
        if (yy < 0 || yy >= 32) continue;
        #pragma unroll
        for (int kx=0; kx<3; ++kx) {
            int xx = x + kx - 1;
            if (xx < 0 || xx >= 32) continue;
            const unsigned short* p = hb + (size_t)(yy*32+xx)*HID2_ + c1;
            bf16x8 d1 = *(const bf16x8*)p;
            bf16x8 d2 = *(const bf16x8*)(p + HID_);
            int t = ky*3 + kx;
            f32x4 w1a = *(const f32x4*)&wt_s[t][co];
            f32x4 w1b = *(const f32x4*)&wt_s[t][co+4];
            f32x4 w2a = *(const f32x4*)&wt_s[t][64+co];
            f32x4 w2b = *(const f32x4*)&wt_s[t][64+co+4];
            #pragma unroll
            for (int j=0;j<4;++j) {
                acc1[j]   += bf2f((unsigned short)d1[j])   * w1a[j];
                acc1[j+4] += bf2f((unsigned short)d1[j+4]) * w1b[j];
                acc2[j]   += bf2f((unsigned short)d2[j])   * w2a[j];
                acc2[j+4] += bf2f((unsigned short)d2[j+4]) * w2b[j];
            }
        }
    }
    bf16x8 o;
    #pragma unroll
    for (int j=0;j<8;++j) {
        float ge = 0.5f*acc1[j]*(1.0f + erff(acc1[j]*0.70710678118f));
        o[j] = (short)f2bf(ge * acc2[j]);
    }
    *(bf16x8*)(g + (size_t)(b*N_ + y*32 + x)*HID_ + c1) = o;
}

extern "C" void kernel_launch(void* const* d_in, const int* in_sizes, int n_in,
                              void* d_out, int out_size, void* d_ws, size_t ws_size,
                              hipStream_t stream) {
    const float* x_in   = (const float*)d_in[0];
    const float* qkv_w  = (const float*)d_in[1];
    const float* qkv_b  = (const float*)d_in[2];
    const float* proj_w = (const float*)d_in[3];
    const float* proj_b = (const float*)d_in[4];
    const float* ln1_g  = (const float*)d_in[5];
    const float* ln1_b  = (const float*)d_in[6];
    const float* ln2_g  = (const float*)d_in[7];
    const float* ln2_b  = (const float*)d_in[8];
    const float* pin_w  = (const float*)d_in[9];
    const float* pin_b  = (const float*)d_in[10];
    const float* dw_w   = (const float*)d_in[11];
    const float* dw_b   = (const float*)d_in[12];
    const float* pout_w = (const float*)d_in[13];
    const float* pout_b = (const float*)d_in[14];

    float* pX = (float*)d_out;                       // residual stream fp32
    unsigned short* wXn  = (unsigned short*)d_ws;                 // [M][384]
    unsigned short* wQKV = wXn  + (size_t)M_*D_;                  // [M][1152]
    unsigned short* wAO  = wQKV + (size_t)M_*3*D_;                // [M][384]
    unsigned short* wH   = wAO  + (size_t)M_*D_;                  // [M][1536]
    unsigned short* wG   = wH   + (size_t)M_*HID2_;               // [M][768]
    unsigned short* wWq  = wG   + (size_t)M_*HID_;                // weights bf16
    unsigned short* wWp  = wWq  + (size_t)2*3*D_*D_;
    unsigned short* wWi  = wWp  + (size_t)2*D_*D_;
    unsigned short* wWo  = wWi  + (size_t)2*HID2_*D_;

    int n1 = 2*3*D_*D_, n2 = 2*D_*D_, n3 = 2*HID2_*D_, n4 = 2*D_*HID_;
    cvt_kernel<<<(n1/4+255)/256, 256, 0, stream>>>(qkv_w,  wWq, n1/4);
    cvt_kernel<<<(n2/4+255)/256, 256, 0, stream>>>(proj_w, wWp, n2/4);
    cvt_kernel<<<(n3/4+255)/256, 256, 0, stream>>>(pin_w,  wWi, n3/4);
    cvt_kernel<<<(n4/4+255)/256, 256, 0, stream>>>(pout_w, wWo, n4/4);

    hipMemcpyAsync(pX, x_in, sizeof(float)*(size_t)M_*D_,
                   hipMemcpyDeviceToDevice, stream);

    for (int l = 0; l < 2; ++l) {
        ln_kernel<<<M_/4, 256, 0, stream>>>(pX, ln1_g + l*D_, ln1_b + l*D_, wXn);
        gemm_bf16<0><<<dim3((3*D_)/128, M_/128), 256, 0, stream>>>(
            wXn, wWq + (size_t)l*3*D_*D_, qkv_b + (size_t)l*3*D_,
            nullptr, wQKV, M_, 3*D_, D_);
        attn_mfma<<<dim3(B_*NH_, N_/64), 256, 0, stream>>>(wQKV, wAO);
        gemm_bf16<1><<<dim3(D_/128, M_/128), 256, 0, stream>>>(
            wAO, wWp + (size_t)l*D_*D_, proj_b + (size_t)l*D_,
            pX, pX, M_, D_, D_);
        ln_kernel<<<M_/4, 256, 0, stream>>>(pX, ln2_g + l*D_, ln2_b + l*D_, wXn);
        gemm_bf16<0><<<dim3(HID2_/128, M_/128), 256, 0, stream>>>(
            wXn, wWi + (size_t)l*HID2_*D_, pin_b + (size_t)l*HID2_,
            nullptr, wH, M_, HID2_, D_);
        dwconv_gate_bf16<<<dim3(HID_/64, 32, B_), 256, 0, stream>>>(
            wH, dw_w + (size_t)l*HID2_*9, dw_b + (size_t)l*HID2_, wG);
        gemm_bf16<1><<<dim3(D_/128, M_/128), 256, 0, stream>>>(
            wG, wWo + (size_t)l*D_*HID_, pout_b + (size_t)l*D_,
            pX, pX, M_, D_, HID_);
    }
}

// Round 6
// 299.056 us; speedup vs baseline: 6.7563x; 1.1193x over previous
//
#include <hip/hip_runtime.h>
#include <math.h>

#define B_ 8
#define N_ 1024
#define D_ 384
#define NH_ 8
#define HD_ 48
#define HID2_ 1536
#define HID_ 768
#define M_ (B_*N_)   /* 8192 */

typedef __attribute__((ext_vector_type(4))) float f32x4;
typedef __attribute__((ext_vector_type(2))) float f32x2;
typedef __attribute__((ext_vector_type(8))) short bf16x8;  // 8 bf16 raw bits
typedef __attribute__((ext_vector_type(4))) short bf16x4;  // 4 bf16 raw bits
typedef __attribute__((ext_vector_type(2))) unsigned u32x2;
typedef __attribute__((ext_vector_type(4))) unsigned u32x4;

__device__ inline unsigned short f2bf(float f) {
    unsigned u = __builtin_bit_cast(unsigned, f);
    u += 0x7fff + ((u >> 16) & 1);        // RNE
    return (unsigned short)(u >> 16);
}
__device__ inline float bf2f(unsigned short h) {
    unsigned u = ((unsigned)h) << 16;
    return __builtin_bit_cast(float, u);
}
__device__ inline unsigned cvtpk_bf16(float lo, float hi) {
    unsigned r;
    asm("v_cvt_pk_bf16_f32 %0, %1, %2" : "=v"(r) : "v"(lo), "v"(hi));
    return r;
}
__device__ inline f32x4 mfma16(bf16x4 a, bf16x4 b, f32x4 c) {
#if __has_builtin(__builtin_amdgcn_mfma_f32_16x16x16bf16_1k)
    return __builtin_amdgcn_mfma_f32_16x16x16bf16_1k(a, b, c, 0, 0, 0);
#else
    asm("v_mfma_f32_16x16x16_bf16 %0, %1, %2, %0" : "+v"(c) : "v"(a), "v"(b));
    return c;
#endif
}

// ------------- fused fp32 -> bf16 convert for 4 weight tensors ------------
__global__ __launch_bounds__(256) void cvt4_kernel(
    const float* __restrict__ s1, const float* __restrict__ s2,
    const float* __restrict__ s3, const float* __restrict__ s4,
    int c1, int c2, int c3, int c4, unsigned short* __restrict__ out) {
    int i = blockIdx.x * 256 + threadIdx.x;
    if (i >= c1 + c2 + c3 + c4) return;
    const float* src; int off = i;
    if (i < c1) { src = s1; }
    else if (i < c1 + c2) { src = s2; off = i - c1; }
    else if (i < c1 + c2 + c3) { src = s3; off = i - c1 - c2; }
    else { src = s4; off = i - c1 - c2 - c3; }
    f32x4 v = *(const f32x4*)(src + (size_t)off*4);
    ushort4 o;
    o.x = f2bf(v[0]); o.y = f2bf(v[1]); o.z = f2bf(v[2]); o.w = f2bf(v[3]);
    *(ushort4*)(out + (size_t)i*4) = o;
}

// ---------------- LayerNorm: one wave per row, bf16 out ----------------
__global__ __launch_bounds__(256) void ln_kernel(
    const float* __restrict__ x, const float* __restrict__ g,
    const float* __restrict__ b, unsigned short* __restrict__ out) {
    int wave = threadIdx.x >> 6;
    int lane = threadIdx.x & 63;
    int row  = blockIdx.x * 4 + wave;
    const float* xr = x + (size_t)row * D_;
    f32x2 v[3];
    float s = 0.f;
    #pragma unroll
    for (int i = 0; i < 3; ++i) {
        v[i] = *(const f32x2*)(xr + i*128 + lane*2);
        s += v[i][0] + v[i][1];
    }
    #pragma unroll
    for (int off = 1; off < 64; off <<= 1) s += __shfl_xor(s, off);
    float mean = s * (1.0f/D_);
    float vs = 0.f;
    #pragma unroll
    for (int i = 0; i < 3; ++i) {
        float t0 = v[i][0]-mean, t1 = v[i][1]-mean;
        vs += t0*t0 + t1*t1;
    }
    #pragma unroll
    for (int off = 1; off < 64; off <<= 1) vs += __shfl_xor(vs, off);
    float rstd = rsqrtf(vs * (1.0f/D_) + 1e-5f);
    unsigned short* orow = out + (size_t)row * D_;
    #pragma unroll
    for (int i = 0; i < 3; ++i) {
        int d = i*128 + lane*2;
        ushort2 o;
        o.x = f2bf((v[i][0]-mean)*rstd*g[d]   + b[d]);
        o.y = f2bf((v[i][1]-mean)*rstd*g[d+1] + b[d+1]);
        *(ushort2*)(orow + d) = o;
    }
}

// ------- bf16 MFMA GEMM, 128x128 tile (for O >= 1024: qkv, pin) ----------
template<int MODE>
__global__ __launch_bounds__(256) void gemm_bf16(
    const unsigned short* __restrict__ A, const unsigned short* __restrict__ W,
    const float* __restrict__ bias, const float* __restrict__ res,
    void* __restrict__ outv, int M, int O, int K) {
    __shared__ unsigned short a_s[128][40];   // stride 80B -> 2-way banks max
    __shared__ unsigned short w_s[128][40];
    int tid = threadIdx.x;
    int o0 = blockIdx.x * 128;
    int m0 = blockIdx.y * 128;
    int wave = tid >> 6, lane = tid & 63;
    int wm = wave >> 1, wn = wave & 1;
    int lr = lane & 15, lc = lane >> 4;
    int r0 = tid >> 2, ch = tid & 3;
    int r1 = r0 + 64;
    f32x4 acc[4][4];
    #pragma unroll
    for (int i=0;i<4;++i)
      #pragma unroll
      for (int j=0;j<4;++j) acc[i][j] = (f32x4){0.f,0.f,0.f,0.f};

    const unsigned short* pa0 = A + (size_t)(m0+r0)*K + ch*8;
    const unsigned short* pa1 = A + (size_t)(m0+r1)*K + ch*8;
    const unsigned short* pw0 = W + (size_t)(o0+r0)*K + ch*8;
    const unsigned short* pw1 = W + (size_t)(o0+r1)*K + ch*8;
    bf16x8 a0 = *(const bf16x8*)pa0, a1 = *(const bf16x8*)pa1;
    bf16x8 w0 = *(const bf16x8*)pw0, w1 = *(const bf16x8*)pw1;

    for (int k0 = 0; k0 < K; k0 += 32) {
        __syncthreads();
        *(bf16x8*)&a_s[r0][ch*8] = a0;
        *(bf16x8*)&a_s[r1][ch*8] = a1;
        *(bf16x8*)&w_s[r0][ch*8] = w0;
        *(bf16x8*)&w_s[r1][ch*8] = w1;
        __syncthreads();
        if (k0 + 32 < K) {
            pa0 += 32; pa1 += 32; pw0 += 32; pw1 += 32;
            a0 = *(const bf16x8*)pa0; a1 = *(const bf16x8*)pa1;
            w0 = *(const bf16x8*)pw0; w1 = *(const bf16x8*)pw1;
        }
        bf16x8 af[4], wf[4];
        #pragma unroll
        for (int i = 0; i < 4; ++i)
            af[i] = *(const bf16x8*)&a_s[wm*64 + i*16 + lr][lc*8];
        #pragma unroll
        for (int j = 0; j < 4; ++j)
            wf[j] = *(const bf16x8*)&w_s[wn*64 + j*16 + lr][lc*8];
        #pragma unroll
        for (int i = 0; i < 4; ++i)
            #pragma unroll
            for (int j = 0; j < 4; ++j)
                acc[i][j] = __builtin_amdgcn_mfma_f32_16x16x32_bf16(
                    af[i], wf[j], acc[i][j], 0, 0, 0);
    }
    #pragma unroll
    for (int i = 0; i < 4; ++i) {
        int mbase = m0 + wm*64 + i*16 + lc*4;
        #pragma unroll
        for (int j = 0; j < 4; ++j) {
            int oc = o0 + wn*64 + j*16 + lr;
            float bv = bias[oc];
            #pragma unroll
            for (int r = 0; r < 4; ++r) {
                int m = mbase + r;
                float v = acc[i][j][r] + bv;
                if (MODE == 1) {
                    ((float*)outv)[(size_t)m*O + oc] = v + res[(size_t)m*O + oc];
                } else {
                    ((unsigned short*)outv)[(size_t)m*O + oc] = f2bf(v);
                }
            }
        }
    }
}

// ------- bf16 MFMA GEMM, 64x64 tile (for small O: proj, pout) ------------
template<int MODE>
__global__ __launch_bounds__(256) void gemm_bf16_s(
    const unsigned short* __restrict__ A, const unsigned short* __restrict__ W,
    const float* __restrict__ bias, const float* __restrict__ res,
    void* __restrict__ outv, int M, int O, int K) {
    __shared__ unsigned short a_s[64][72];
    __shared__ unsigned short w_s[64][72];
    int tid = threadIdx.x;
    int o0 = blockIdx.x * 64;
    int m0 = blockIdx.y * 64;
    int wave = tid >> 6, lane = tid & 63;
    int lr = lane & 15, lc = lane >> 4;
    int r = tid >> 2, c = (tid & 3) * 16;
    f32x4 acc[4];
    #pragma unroll
    for (int i=0;i<4;++i) acc[i] = (f32x4){0.f,0.f,0.f,0.f};

    const unsigned short* pa = A + (size_t)(m0+r)*K + c;
    const unsigned short* pw = W + (size_t)(o0+r)*K + c;
    bf16x8 a0 = *(const bf16x8*)pa, a1 = *(const bf16x8*)(pa+8);
    bf16x8 w0 = *(const bf16x8*)pw, w1 = *(const bf16x8*)(pw+8);

    for (int k0 = 0; k0 < K; k0 += 64) {
        __syncthreads();
        *(bf16x8*)&a_s[r][c]   = a0;
        *(bf16x8*)&a_s[r][c+8] = a1;
        *(bf16x8*)&w_s[r][c]   = w0;
        *(bf16x8*)&w_s[r][c+8] = w1;
        __syncthreads();
        if (k0 + 64 < K) {
            pa += 64; pw += 64;
            a0 = *(const bf16x8*)pa; a1 = *(const bf16x8*)(pa+8);
            w0 = *(const bf16x8*)pw; w1 = *(const bf16x8*)(pw+8);
        }
        #pragma unroll
        for (int ks = 0; ks < 2; ++ks) {
            bf16x8 wf = *(const bf16x8*)&w_s[wave*16 + lr][ks*32 + lc*8];
            #pragma unroll
            for (int i = 0; i < 4; ++i) {
                bf16x8 af = *(const bf16x8*)&a_s[i*16 + lr][ks*32 + lc*8];
                acc[i] = __builtin_amdgcn_mfma_f32_16x16x32_bf16(af, wf, acc[i], 0,0,0);
            }
        }
    }
    int oc = o0 + wave*16 + lr;
    float bv = bias[oc];
    #pragma unroll
    for (int i = 0; i < 4; ++i) {
        #pragma unroll
        for (int rr = 0; rr < 4; ++rr) {
            int m = m0 + i*16 + lc*4 + rr;
            float v = acc[i][rr] + bv;
            if (MODE == 1) {
                ((float*)outv)[(size_t)m*O + oc] = v + res[(size_t)m*O + oc];
            } else {
                ((unsigned short*)outv)[(size_t)m*O + oc] = f2bf(v);
            }
        }
    }
}

// ---------------- Flash attention, swapped-operand MFMA -------------------
// grid (B*NH, N/64), 256 thr = 4 waves; wave w owns q rows q0+w*16..+15.
// K staged in LDS once per block (shared by 4 waves); V^T in LDS with
// 2-way-bank write mapping. Per-tile unconditional rescale (R4 numerics).
__global__ __launch_bounds__(256) void attn_mfma(
    const unsigned short* __restrict__ qkv, unsigned short* __restrict__ out) {
    __shared__ unsigned short k_s[64][72];    // [kv][d], cols 48..71 stay zero
    __shared__ unsigned short vt_s[48][72];   // [d][kv]
    int tid = threadIdx.x;
    int wave = tid >> 6, lane = tid & 63;
    int lr = lane & 15, lc = lane >> 4;
    int b = blockIdx.x >> 3, h = blockIdx.x & 7;
    int q0 = blockIdx.y * 64;
    const float LOG2E = 1.4426950408889634f;
    float decay = logf(1.0f - exp2f(-2.0f - 0.5f*(float)h)) * LOG2E; // <0
    const float scale2 = 0.14433756729740643f * LOG2E;
    const bf16x8 zero8 = {0,0,0,0,0,0,0,0};

    // zero the k_s pad region once (never rewritten)
    if (tid < 192) {
        int zr = tid / 3, zc = 48 + (tid % 3) * 8;
        *(bf16x8*)&k_s[zr][zc] = zero8;
    }

    int q = q0 + wave*16 + lr;
    float qqf = (float)q;
    const unsigned short* qrow = qkv + ((size_t)b*N_ + q)*1152 + h*48;
    bf16x8 qf0 = *(const bf16x8*)(qrow + lc*8);
    bf16x8 qf1 = zero8;
    if (lc < 2) qf1 = *(const bf16x8*)(qrow + 32 + lc*8);

    // K staging: chunk s -> row s/6, col (s%6)*8 ; thread covers s=tid and
    // (tid<128) s=tid+256.
    const unsigned short* kbase = qkv + (size_t)b*N_*1152 + D_ + h*48;
    int kr0 = tid / 6, kc0 = (tid % 6) * 8;
    bool kact1 = tid < 128;
    int s1 = kact1 ? tid + 256 : 0;
    int kr1 = s1 / 6, kc1 = (s1 % 6) * 8;
    const unsigned short* kp0 = kbase + (size_t)kr0*1152 + kc0;
    const unsigned short* kp1 = kbase + (size_t)kr1*1152 + kc1;

    // V staging: thread t<192 owns d-pair vd2=(t>>3)*2, kv-chunk vch=t&7
    int vd2 = (tid >> 3) * 2;
    int vch = tid & 7;
    bool vact = tid < 192;
    const unsigned short* vp = kbase + D_ + (size_t)(vch*8)*1152 + vd2;

    float m_i = -3e38f, l_i = 0.f;
    f32x4 oacc[3];
    #pragma unroll
    for (int i=0;i<3;++i) oacc[i] = (f32x4){0.f,0.f,0.f,0.f};

    for (int kt = 0; kt < 16; ++kt) {
        int n0 = kt * 64;
        // issue this tile's global loads (K chunks + V u32 gather)
        bf16x8 kv0 = *(const bf16x8*)kp0;  kp0 += 64*1152;
        bf16x8 kv1 = zero8;
        if (kact1) kv1 = *(const bf16x8*)kp1;
        kp1 += 64*1152;
        unsigned vv[8];
        if (vact) {
            #pragma unroll
            for (int i = 0; i < 8; ++i)
                vv[i] = *(const unsigned*)(vp + (size_t)i*1152);
        }
        vp += 64*1152;
        __syncthreads();   // prev tile's k_s/vt_s reads done
        *(bf16x8*)&k_s[kr0][kc0] = kv0;
        if (kact1) *(bf16x8*)&k_s[kr1][kc1] = kv1;
        if (vact) {
            u32x4 wlo, whi;
            #pragma unroll
            for (int i = 0; i < 4; ++i) {
                wlo[i] = (vv[2*i] & 0xffffu) | (vv[2*i+1] << 16);
                whi[i] = (vv[2*i] >> 16)    | (vv[2*i+1] & 0xffff0000u);
            }
            *(bf16x8*)&vt_s[vd2]  [vch*8] = __builtin_bit_cast(bf16x8, wlo);
            *(bf16x8*)&vt_s[vd2+1][vch*8] = __builtin_bit_cast(bf16x8, whi);
        }
        __syncthreads();
        // S^T = K . Q^T : sc[f][r] = score(q=lr, k=n0+f*16+lc*4+r)
        f32x4 sc[4];
        #pragma unroll
        for (int f = 0; f < 4; ++f) {
            sc[f] = (f32x4){0.f,0.f,0.f,0.f};
            bf16x8 kf0 = *(const bf16x8*)&k_s[f*16 + lr][lc*8];
            bf16x8 kf1 = *(const bf16x8*)&k_s[f*16 + lr][32 + lc*8]; // pad=0
            sc[f] = __builtin_amdgcn_mfma_f32_16x16x32_bf16(kf0, qf0, sc[f],0,0,0);
            sc[f] = __builtin_amdgcn_mfma_f32_16x16x32_bf16(kf1, qf1, sc[f],0,0,0);
        }
        // bias + max (log2 domain)
        float s2[4][4];
        float kv0f = (float)(n0 + lc*4);
        float mt = -3e38f;
        #pragma unroll
        for (int f = 0; f < 4; ++f)
            #pragma unroll
            for (int r = 0; r < 4; ++r) {
                float kk = kv0f + (float)(f*16 + r);
                s2[f][r] = sc[f][r]*scale2 + fabsf(qqf - kk)*decay;
                mt = fmaxf(mt, s2[f][r]);
            }
        mt = fmaxf(mt, __shfl_xor(mt, 16));
        mt = fmaxf(mt, __shfl_xor(mt, 32));
        // unconditional per-tile rescale (R4 numerics)
        float mn = fmaxf(m_i, mt);
        float alpha = __builtin_amdgcn_exp2f(m_i - mn);
        m_i = mn;
        l_i *= alpha;
        #pragma unroll
        for (int md = 0; md < 3; ++md)
            #pragma unroll
            for (int r = 0; r < 4; ++r) oacc[md][r] *= alpha;
        float ps = 0.f;
        #pragma unroll
        for (int f = 0; f < 4; ++f)
            #pragma unroll
            for (int r = 0; r < 4; ++r) {
                s2[f][r] = __builtin_amdgcn_exp2f(s2[f][r] - m_i);
                ps += s2[f][r];
            }
        ps += __shfl_xor(ps, 16);
        ps += __shfl_xor(ps, 32);
        l_i += ps;
        // P fragments (T12 pack)
        bf16x4 pfrag[4];
        #pragma unroll
        for (int f = 0; f < 4; ++f) {
            u32x2 u;
            u[0] = cvtpk_bf16(s2[f][0], s2[f][1]);
            u[1] = cvtpk_bf16(s2[f][2], s2[f][3]);
            pfrag[f] = __builtin_bit_cast(bf16x4, u);
        }
        // O^T += V^T . P^T
        #pragma unroll
        for (int f = 0; f < 4; ++f)
            #pragma unroll
            for (int md = 0; md < 3; ++md) {
                bf16x4 va = *(const bf16x4*)&vt_s[md*16 + lr][f*16 + lc*4];
                oacc[md] = mfma16(va, pfrag[f], oacc[md]);
            }
    }
    float inv_l = 1.0f / l_i;
    #pragma unroll
    for (int md = 0; md < 3; ++md) {
        ushort4 o;
        o.x = f2bf(oacc[md][0]*inv_l);
        o.y = f2bf(oacc[md][1]*inv_l);
        o.z = f2bf(oacc[md][2]*inv_l);
        o.w = f2bf(oacc[md][3]*inv_l);
        *(ushort4*)(out + ((size_t)b*N_ + q)*D_ + h*48 + md*16 + lc*4) = o;
    }
}

// ---------------- Depthwise 3x3 conv + GELU gate, 8 ch/thread ------------
__global__ __launch_bounds__(256) void dwconv_gate_bf16(
    const unsigned short* __restrict__ h, const float* __restrict__ dw_w,
    const float* __restrict__ dw_b, unsigned short* __restrict__ g) {
    __shared__ float wt_s[9][128];   // [tap][ch: 0..63 = h1, 64..127 = h2]
    __shared__ float bs_s[128];
    int tid = threadIdx.x;
    int cg0 = blockIdx.x * 64;
    int y   = blockIdx.y;
    int b   = blockIdx.z;
    for (int i = tid; i < 1152; i += 256) {
        int tap = i >> 7, cl = i & 127;
        int gch = (cl < 64) ? (cg0 + cl) : (HID_ + cg0 + (cl - 64));
        wt_s[tap][cl] = dw_w[(size_t)gch*9 + tap];
    }
    if (tid < 128) {
        int gch = (tid < 64) ? (cg0 + tid) : (HID_ + cg0 + (tid - 64));
        bs_s[tid] = dw_b[gch];
    }
    __syncthreads();
    int x  = tid >> 3;
    int co = (tid & 7) * 8;
    int c1 = cg0 + co;
    const unsigned short* hb = h + (size_t)b*N_*HID2_;
    float acc1[8], acc2[8];
    #pragma unroll
    for (int j=0;j<8;++j) { acc1[j] = bs_s[co+j]; acc2[j] = bs_s[64+co+j]; }
    #pragma unroll
    for (int ky=0; ky<3; ++ky) {
        int yy = y + ky - 1;
        if (yy < 0 || yy >= 32) continue;
        #pragma unroll
        for (int kx=0; kx<3; ++kx) {
            int xx = x + kx - 1;
            if (xx < 0 || xx >= 32) continue;
            const unsigned short* p = hb + (size_t)(yy*32+xx)*HID2_ + c1;
            bf16x8 d1 = *(const bf16x8*)p;
            bf16x8 d2 = *(const bf16x8*)(p + HID_);
            int t = ky*3 + kx;
            f32x4 w1a = *(const f32x4*)&wt_s[t][co];
            f32x4 w1b = *(const f32x4*)&wt_s[t][co+4];
            f32x4 w2a = *(const f32x4*)&wt_s[t][64+co];
            f32x4 w2b = *(const f32x4*)&wt_s[t][64+co+4];
            #pragma unroll
            for (int j=0;j<4;++j) {
                acc1[j]   += bf2f((unsigned short)d1[j])   * w1a[j];
                acc1[j+4] += bf2f((unsigned short)d1[j+4]) * w1b[j];
                acc2[j]   += bf2f((unsigned short)d2[j])   * w2a[j];
                acc2[j+4] += bf2f((unsigned short)d2[j+4]) * w2b[j];
            }
        }
    }
    bf16x8 o;
    #pragma unroll
    for (int j=0;j<8;++j) {
        float ge = 0.5f*acc1[j]*(1.0f + erff(acc1[j]*0.70710678118f));
        o[j] = (short)f2bf(ge * acc2[j]);
    }
    *(bf16x8*)(g + (size_t)(b*N_ + y*32 + x)*HID_ + c1) = o;
}

extern "C" void kernel_launch(void* const* d_in, const int* in_sizes, int n_in,
                              void* d_out, int out_size, void* d_ws, size_t ws_size,
                              hipStream_t stream) {
    const float* x_in   = (const float*)d_in[0];
    const float* qkv_w  = (const float*)d_in[1];
    const float* qkv_b  = (const float*)d_in[2];
    const float* proj_w = (const float*)d_in[3];
    const float* proj_b = (const float*)d_in[4];
    const float* ln1_g  = (const float*)d_in[5];
    const float* ln1_b  = (const float*)d_in[6];
    const float* ln2_g  = (const float*)d_in[7];
    const float* ln2_b  = (const float*)d_in[8];
    const float* pin_w  = (const float*)d_in[9];
    const float* pin_b  = (const float*)d_in[10];
    const float* dw_w   = (const float*)d_in[11];
    const float* dw_b   = (const float*)d_in[12];
    const float* pout_w = (const float*)d_in[13];
    const float* pout_b = (const float*)d_in[14];

    float* pX = (float*)d_out;                       // residual stream fp32
    unsigned short* wXn  = (unsigned short*)d_ws;                 // [M][384]
    unsigned short* wQKV = wXn  + (size_t)M_*D_;                  // [M][1152]
    unsigned short* wAO  = wQKV + (size_t)M_*3*D_;                // [M][384]
    unsigned short* wH   = wAO  + (size_t)M_*D_;                  // [M][1536]
    unsigned short* wG   = wH   + (size_t)M_*HID2_;               // [M][768]
    unsigned short* wWq  = wG   + (size_t)M_*HID_;                // weights bf16
    unsigned short* wWp  = wWq  + (size_t)2*3*D_*D_;
    unsigned short* wWi  = wWp  + (size_t)2*D_*D_;
    unsigned short* wWo  = wWi  + (size_t)2*HID2_*D_;

    int c1 = 2*3*D_*D_/4, c2 = 2*D_*D_/4, c3 = 2*HID2_*D_/4, c4 = 2*D_*HID_/4;
    int ctot = c1 + c2 + c3 + c4;
    cvt4_kernel<<<(ctot+255)/256, 256, 0, stream>>>(
        qkv_w, proj_w, pin_w, pout_w, c1, c2, c3, c4, wWq);

    hipMemcpyAsync(pX, x_in, sizeof(float)*(size_t)M_*D_,
                   hipMemcpyDeviceToDevice, stream);

    for (int l = 0; l < 2; ++l) {
        ln_kernel<<<M_/4, 256, 0, stream>>>(pX, ln1_g + l*D_, ln1_b + l*D_, wXn);
        gemm_bf16<0><<<dim3((3*D_)/128, M_/128), 256, 0, stream>>>(
            wXn, wWq + (size_t)l*3*D_*D_, qkv_b + (size_t)l*3*D_,
            nullptr, wQKV, M_, 3*D_, D_);
        attn_mfma<<<dim3(B_*NH_, N_/64), 256, 0, stream>>>(wQKV, wAO);
        gemm_bf16_s<1><<<dim3(D_/64, M_/64), 256, 0, stream>>>(
            wAO, wWp + (size_t)l*D_*D_, proj_b + (size_t)l*D_,
            pX, pX, M_, D_, D_);
        ln_kernel<<<M_/4, 256, 0, stream>>>(pX, ln2_g + l*D_, ln2_b + l*D_, wXn);
        gemm_bf16<0><<<dim3(HID2_/128, M_/128), 256, 0, stream>>>(
            wXn, wWi + (size_t)l*HID2_*D_, pin_b + (size_t)l*HID2_,
            nullptr, wH, M_, HID2_, D_);
        dwconv_gate_bf16<<<dim3(HID_/64, 32, B_), 256, 0, stream>>>(
            wH, dw_w + (size_t)l*HID2_*9, dw_b + (size_t)l*HID2_, wG);
        gemm_bf16_s<1><<<dim3(D_/64, M_/64), 256, 0, stream>>>(
            wG, wWo + (size_t)l*D_*HID_, pout_b + (size_t)l*D_,
            pX, pX, M_, D_, HID_);
    }
}

// Round 7
// 294.938 us; speedup vs baseline: 6.8506x; 1.0140x over previous
//
#include <hip/hip_runtime.h>
#include <math.h>

#define B_ 8
#define N_ 1024
#define D_ 384
#define NH_ 8
#define HD_ 48
#define HID2_ 1536
#define HID_ 768
#define M_ (B_*N_)   /* 8192 */

typedef __attribute__((ext_vector_type(4))) float f32x4;
typedef __attribute__((ext_vector_type(2))) float f32x2;
typedef __attribute__((ext_vector_type(8))) short bf16x8;  // 8 bf16 raw bits
typedef __attribute__((ext_vector_type(4))) short bf16x4;  // 4 bf16 raw bits
typedef __attribute__((ext_vector_type(2))) unsigned u32x2;
typedef __attribute__((ext_vector_type(4))) unsigned u32x4;

__device__ inline unsigned short f2bf(float f) {
    unsigned u = __builtin_bit_cast(unsigned, f);
    u += 0x7fff + ((u >> 16) & 1);        // RNE
    return (unsigned short)(u >> 16);
}
__device__ inline float bf2f(unsigned short h) {
    unsigned u = ((unsigned)h) << 16;
    return __builtin_bit_cast(float, u);
}
__device__ inline unsigned cvtpk_bf16(float lo, float hi) {
    unsigned r;
    asm("v_cvt_pk_bf16_f32 %0, %1, %2" : "=v"(r) : "v"(lo), "v"(hi));
    return r;
}
__device__ inline f32x4 mfma16(bf16x4 a, bf16x4 b, f32x4 c) {
#if __has_builtin(__builtin_amdgcn_mfma_f32_16x16x16bf16_1k)
    return __builtin_amdgcn_mfma_f32_16x16x16bf16_1k(a, b, c, 0, 0, 0);
#else
    asm("v_mfma_f32_16x16x16_bf16 %0, %1, %2, %0" : "+v"(c) : "v"(a), "v"(b));
    return c;
#endif
}

// ------------- fused fp32 -> bf16 convert for 4 weight tensors ------------
__global__ __launch_bounds__(256) void cvt4_kernel(
    const float* __restrict__ s1, const float* __restrict__ s2,
    const float* __restrict__ s3, const float* __restrict__ s4,
    int c1, int c2, int c3, int c4, unsigned short* __restrict__ out) {
    int i = blockIdx.x * 256 + threadIdx.x;
    if (i >= c1 + c2 + c3 + c4) return;
    const float* src; int off = i;
    if (i < c1) { src = s1; }
    else if (i < c1 + c2) { src = s2; off = i - c1; }
    else if (i < c1 + c2 + c3) { src = s3; off = i - c1 - c2; }
    else { src = s4; off = i - c1 - c2 - c3; }
    f32x4 v = *(const f32x4*)(src + (size_t)off*4);
    ushort4 o;
    o.x = f2bf(v[0]); o.y = f2bf(v[1]); o.z = f2bf(v[2]); o.w = f2bf(v[3]);
    *(ushort4*)(out + (size_t)i*4) = o;
}

// ---------------- LayerNorm: one wave per row, bf16 out ----------------
__global__ __launch_bounds__(256) void ln_kernel(
    const float* __restrict__ x, const float* __restrict__ g,
    const float* __restrict__ b, unsigned short* __restrict__ out) {
    int wave = threadIdx.x >> 6;
    int lane = threadIdx.x & 63;
    int row  = blockIdx.x * 4 + wave;
    const float* xr = x + (size_t)row * D_;
    f32x2 v[3];
    float s = 0.f;
    #pragma unroll
    for (int i = 0; i < 3; ++i) {
        v[i] = *(const f32x2*)(xr + i*128 + lane*2);
        s += v[i][0] + v[i][1];
    }
    #pragma unroll
    for (int off = 1; off < 64; off <<= 1) s += __shfl_xor(s, off);
    float mean = s * (1.0f/D_);
    float vs = 0.f;
    #pragma unroll
    for (int i = 0; i < 3; ++i) {
        float t0 = v[i][0]-mean, t1 = v[i][1]-mean;
        vs += t0*t0 + t1*t1;
    }
    #pragma unroll
    for (int off = 1; off < 64; off <<= 1) vs += __shfl_xor(vs, off);
    float rstd = rsqrtf(vs * (1.0f/D_) + 1e-5f);
    unsigned short* orow = out + (size_t)row * D_;
    #pragma unroll
    for (int i = 0; i < 3; ++i) {
        int d = i*128 + lane*2;
        ushort2 o;
        o.x = f2bf((v[i][0]-mean)*rstd*g[d]   + b[d]);
        o.y = f2bf((v[i][1]-mean)*rstd*g[d+1] + b[d+1]);
        *(ushort2*)(orow + d) = o;
    }
}

// ------- bf16 MFMA GEMM, 128x128 tile (for O >= 1024: qkv, pin) ----------
template<int MODE>
__global__ __launch_bounds__(256) void gemm_bf16(
    const unsigned short* __restrict__ A, const unsigned short* __restrict__ W,
    const float* __restrict__ bias, const float* __restrict__ res,
    void* __restrict__ outv, int M, int O, int K) {
    __shared__ unsigned short a_s[128][40];   // stride 80B -> 2-way banks max
    __shared__ unsigned short w_s[128][40];
    int tid = threadIdx.x;
    int o0 = blockIdx.x * 128;
    int m0 = blockIdx.y * 128;
    int wave = tid >> 6, lane = tid & 63;
    int wm = wave >> 1, wn = wave & 1;
    int lr = lane & 15, lc = lane >> 4;
    int r0 = tid >> 2, ch = tid & 3;
    int r1 = r0 + 64;
    f32x4 acc[4][4];
    #pragma unroll
    for (int i=0;i<4;++i)
      #pragma unroll
      for (int j=0;j<4;++j) acc[i][j] = (f32x4){0.f,0.f,0.f,0.f};

    const unsigned short* pa0 = A + (size_t)(m0+r0)*K + ch*8;
    const unsigned short* pa1 = A + (size_t)(m0+r1)*K + ch*8;
    const unsigned short* pw0 = W + (size_t)(o0+r0)*K + ch*8;
    const unsigned short* pw1 = W + (size_t)(o0+r1)*K + ch*8;
    bf16x8 a0 = *(const bf16x8*)pa0, a1 = *(const bf16x8*)pa1;
    bf16x8 w0 = *(const bf16x8*)pw0, w1 = *(const bf16x8*)pw1;

    for (int k0 = 0; k0 < K; k0 += 32) {
        __syncthreads();
        *(bf16x8*)&a_s[r0][ch*8] = a0;
        *(bf16x8*)&a_s[r1][ch*8] = a1;
        *(bf16x8*)&w_s[r0][ch*8] = w0;
        *(bf16x8*)&w_s[r1][ch*8] = w1;
        __syncthreads();
        if (k0 + 32 < K) {
            pa0 += 32; pa1 += 32; pw0 += 32; pw1 += 32;
            a0 = *(const bf16x8*)pa0; a1 = *(const bf16x8*)pa1;
            w0 = *(const bf16x8*)pw0; w1 = *(const bf16x8*)pw1;
        }
        bf16x8 af[4], wf[4];
        #pragma unroll
        for (int i = 0; i < 4; ++i)
            af[i] = *(const bf16x8*)&a_s[wm*64 + i*16 + lr][lc*8];
        #pragma unroll
        for (int j = 0; j < 4; ++j)
            wf[j] = *(const bf16x8*)&w_s[wn*64 + j*16 + lr][lc*8];
        #pragma unroll
        for (int i = 0; i < 4; ++i)
            #pragma unroll
            for (int j = 0; j < 4; ++j)
                acc[i][j] = __builtin_amdgcn_mfma_f32_16x16x32_bf16(
                    af[i], wf[j], acc[i][j], 0, 0, 0);
    }
    #pragma unroll
    for (int i = 0; i < 4; ++i) {
        int mbase = m0 + wm*64 + i*16 + lc*4;
        #pragma unroll
        for (int j = 0; j < 4; ++j) {
            int oc = o0 + wn*64 + j*16 + lr;
            float bv = bias[oc];
            #pragma unroll
            for (int r = 0; r < 4; ++r) {
                int m = mbase + r;
                float v = acc[i][j][r] + bv;
                if (MODE == 1) {
                    ((float*)outv)[(size_t)m*O + oc] = v + res[(size_t)m*O + oc];
                } else {
                    ((unsigned short*)outv)[(size_t)m*O + oc] = f2bf(v);
                }
            }
        }
    }
}

// ------- bf16 MFMA GEMM, 64x64 tile (for small O: proj, pout) ------------
template<int MODE>
__global__ __launch_bounds__(256) void gemm_bf16_s(
    const unsigned short* __restrict__ A, const unsigned short* __restrict__ W,
    const float* __restrict__ bias, const float* __restrict__ res,
    void* __restrict__ outv, int M, int O, int K) {
    __shared__ unsigned short a_s[64][72];
    __shared__ unsigned short w_s[64][72];
    int tid = threadIdx.x;
    int o0 = blockIdx.x * 64;
    int m0 = blockIdx.y * 64;
    int wave = tid >> 6, lane = tid & 63;
    int lr = lane & 15, lc = lane >> 4;
    int r = tid >> 2, c = (tid & 3) * 16;
    f32x4 acc[4];
    #pragma unroll
    for (int i=0;i<4;++i) acc[i] = (f32x4){0.f,0.f,0.f,0.f};

    const unsigned short* pa = A + (size_t)(m0+r)*K + c;
    const unsigned short* pw = W + (size_t)(o0+r)*K + c;
    bf16x8 a0 = *(const bf16x8*)pa, a1 = *(const bf16x8*)(pa+8);
    bf16x8 w0 = *(const bf16x8*)pw, w1 = *(const bf16x8*)(pw+8);

    for (int k0 = 0; k0 < K; k0 += 64) {
        __syncthreads();
        *(bf16x8*)&a_s[r][c]   = a0;
        *(bf16x8*)&a_s[r][c+8] = a1;
        *(bf16x8*)&w_s[r][c]   = w0;
        *(bf16x8*)&w_s[r][c+8] = w1;
        __syncthreads();
        if (k0 + 64 < K) {
            pa += 64; pw += 64;
            a0 = *(const bf16x8*)pa; a1 = *(const bf16x8*)(pa+8);
            w0 = *(const bf16x8*)pw; w1 = *(const bf16x8*)(pw+8);
        }
        #pragma unroll
        for (int ks = 0; ks < 2; ++ks) {
            bf16x8 wf = *(const bf16x8*)&w_s[wave*16 + lr][ks*32 + lc*8];
            #pragma unroll
            for (int i = 0; i < 4; ++i) {
                bf16x8 af = *(const bf16x8*)&a_s[i*16 + lr][ks*32 + lc*8];
                acc[i] = __builtin_amdgcn_mfma_f32_16x16x32_bf16(af, wf, acc[i], 0,0,0);
            }
        }
    }
    int oc = o0 + wave*16 + lr;
    float bv = bias[oc];
    #pragma unroll
    for (int i = 0; i < 4; ++i) {
        #pragma unroll
        for (int rr = 0; rr < 4; ++rr) {
            int m = m0 + i*16 + lc*4 + rr;
            float v = acc[i][rr] + bv;
            if (MODE == 1) {
                ((float*)outv)[(size_t)m*O + oc] = v + res[(size_t)m*O + oc];
            } else {
                ((unsigned short*)outv)[(size_t)m*O + oc] = f2bf(v);
            }
        }
    }
}

// ---------------- Flash attention, swapped-operand MFMA -------------------
// grid (B*NH, N/64), 256 thr = 4 waves; wave w owns q rows q0+w*16..+15.
// Band-skip: decay bias makes attention banded; tiles whose min |i-j| puts
// the whole tile's bias 20+ nats below the (always kept) diagonal tile are
// skipped. Bounds are block-uniform -> no divergence, barriers legal.
// Computed tiles are numerically identical to the full version.
__global__ __launch_bounds__(256) void attn_mfma(
    const unsigned short* __restrict__ qkv, unsigned short* __restrict__ out) {
    __shared__ unsigned short k_s[64][72];    // [kv][d], cols 48..71 stay zero
    __shared__ unsigned short vt_s[48][72];   // [d][kv]
    int tid = threadIdx.x;
    int wave = tid >> 6, lane = tid & 63;
    int lr = lane & 15, lc = lane >> 4;
    int b = blockIdx.x >> 3, h = blockIdx.x & 7;
    int q0 = blockIdx.y * 64;
    const float LOG2E = 1.4426950408889634f;
    float decay_nats = logf(1.0f - exp2f(-2.0f - 0.5f*(float)h));  // < 0
    float decay = decay_nats * LOG2E;
    const float scale2 = 0.14433756729740643f * LOG2E;
    const bf16x8 zero8 = {0,0,0,0,0,0,0,0};

    // band-skip tile range (block-uniform)
    int bandi = (int)(20.0f / (-decay_nats));
    int lo = q0 - bandi - 63;
    int kt_lo = lo > 0 ? (lo >> 6) : 0;
    int kt_hi = (q0 + 63 + bandi) >> 6;
    if (kt_hi > 15) kt_hi = 15;

    // zero the k_s pad region once (never rewritten)
    if (tid < 192) {
        int zr = tid / 3, zc = 48 + (tid % 3) * 8;
        *(bf16x8*)&k_s[zr][zc] = zero8;
    }

    int q = q0 + wave*16 + lr;
    float qqf = (float)q;
    const unsigned short* qrow = qkv + ((size_t)b*N_ + q)*1152 + h*48;
    bf16x8 qf0 = *(const bf16x8*)(qrow + lc*8);
    bf16x8 qf1 = zero8;
    if (lc < 2) qf1 = *(const bf16x8*)(qrow + 32 + lc*8);

    // K staging: chunk s -> row s/6, col (s%6)*8 ; thread covers s=tid and
    // (tid<128) s=tid+256.
    const unsigned short* kbase = qkv + (size_t)b*N_*1152 + D_ + h*48;
    int kr0 = tid / 6, kc0 = (tid % 6) * 8;
    bool kact1 = tid < 128;
    int s1 = kact1 ? tid + 256 : 0;
    int kr1 = s1 / 6, kc1 = (s1 % 6) * 8;
    const unsigned short* kp0 = kbase + (size_t)(kt_lo*64 + kr0)*1152 + kc0;
    const unsigned short* kp1 = kbase + (size_t)(kt_lo*64 + kr1)*1152 + kc1;

    // V staging: thread t<192 owns d-pair vd2=(t>>3)*2, kv-chunk vch=t&7
    int vd2 = (tid >> 3) * 2;
    int vch = tid & 7;
    bool vact = tid < 192;
    const unsigned short* vp = kbase + D_ + (size_t)(kt_lo*64 + vch*8)*1152 + vd2;

    float m_i = -3e38f, l_i = 0.f;
    f32x4 oacc[3];
    #pragma unroll
    for (int i=0;i<3;++i) oacc[i] = (f32x4){0.f,0.f,0.f,0.f};

    for (int kt = kt_lo; kt <= kt_hi; ++kt) {
        int n0 = kt * 64;
        // issue this tile's global loads (K chunks + V u32 gather)
        bf16x8 kv0 = *(const bf16x8*)kp0;  kp0 += 64*1152;
        bf16x8 kv1 = zero8;
        if (kact1) kv1 = *(const bf16x8*)kp1;
        kp1 += 64*1152;
        unsigned vv[8];
        if (vact) {
            #pragma unroll
            for (int i = 0; i < 8; ++i)
                vv[i] = *(const unsigned*)(vp + (size_t)i*1152);
        }
        vp += 64*1152;
        __syncthreads();   // prev tile's k_s/vt_s reads done
        *(bf16x8*)&k_s[kr0][kc0] = kv0;
        if (kact1) *(bf16x8*)&k_s[kr1][kc1] = kv1;
        if (vact) {
            u32x4 wlo, whi;
            #pragma unroll
            for (int i = 0; i < 4; ++i) {
                wlo[i] = (vv[2*i] & 0xffffu) | (vv[2*i+1] << 16);
                whi[i] = (vv[2*i] >> 16)    | (vv[2*i+1] & 0xffff0000u);
            }
            *(bf16x8*)&vt_s[vd2]  [vch*8] = __builtin_bit_cast(bf16x8, wlo);
            *(bf16x8*)&vt_s[vd2+1][vch*8] = __builtin_bit_cast(bf16x8, whi);
        }
        __syncthreads();
        // S^T = K . Q^T : sc[f][r] = score(q=lr, k=n0+f*16+lc*4+r)
        f32x4 sc[4];
        #pragma unroll
        for (int f = 0; f < 4; ++f) {
            sc[f] = (f32x4){0.f,0.f,0.f,0.f};
            bf16x8 kf0 = *(const bf16x8*)&k_s[f*16 + lr][lc*8];
            bf16x8 kf1 = *(const bf16x8*)&k_s[f*16 + lr][32 + lc*8]; // pad=0
            sc[f] = __builtin_amdgcn_mfma_f32_16x16x32_bf16(kf0, qf0, sc[f],0,0,0);
            sc[f] = __builtin_amdgcn_mfma_f32_16x16x32_bf16(kf1, qf1, sc[f],0,0,0);
        }
        // bias + max (log2 domain)
        float s2[4][4];
        float kv0f = (float)(n0 + lc*4);
        float mt = -3e38f;
        #pragma unroll
        for (int f = 0; f < 4; ++f)
            #pragma unroll
            for (int r = 0; r < 4; ++r) {
                float kk = kv0f + (float)(f*16 + r);
                s2[f][r] = sc[f][r]*scale2 + fabsf(qqf - kk)*decay;
                mt = fmaxf(mt, s2[f][r]);
            }
        mt = fmaxf(mt, __shfl_xor(mt, 16));
        mt = fmaxf(mt, __shfl_xor(mt, 32));
        // unconditional per-tile rescale
        float mn = fmaxf(m_i, mt);
        float alpha = __builtin_amdgcn_exp2f(m_i - mn);
        m_i = mn;
        l_i *= alpha;
        #pragma unroll
        for (int md = 0; md < 3; ++md)
            #pragma unroll
            for (int r = 0; r < 4; ++r) oacc[md][r] *= alpha;
        float ps = 0.f;
        #pragma unroll
        for (int f = 0; f < 4; ++f)
            #pragma unroll
            for (int r = 0; r < 4; ++r) {
                s2[f][r] = __builtin_amdgcn_exp2f(s2[f][r] - m_i);
                ps += s2[f][r];
            }
        ps += __shfl_xor(ps, 16);
        ps += __shfl_xor(ps, 32);
        l_i += ps;
        // P fragments (T12 pack)
        bf16x4 pfrag[4];
        #pragma unroll
        for (int f = 0; f < 4; ++f) {
            u32x2 u;
            u[0] = cvtpk_bf16(s2[f][0], s2[f][1]);
            u[1] = cvtpk_bf16(s2[f][2], s2[f][3]);
            pfrag[f] = __builtin_bit_cast(bf16x4, u);
        }
        // O^T += V^T . P^T
        #pragma unroll
        for (int f = 0; f < 4; ++f)
            #pragma unroll
            for (int md = 0; md < 3; ++md) {
                bf16x4 va = *(const bf16x4*)&vt_s[md*16 + lr][f*16 + lc*4];
                oacc[md] = mfma16(va, pfrag[f], oacc[md]);
            }
    }
    float inv_l = 1.0f / l_i;
    #pragma unroll
    for (int md = 0; md < 3; ++md) {
        ushort4 o;
        o.x = f2bf(oacc[md][0]*inv_l);
        o.y = f2bf(oacc[md][1]*inv_l);
        o.z = f2bf(oacc[md][2]*inv_l);
        o.w = f2bf(oacc[md][3]*inv_l);
        *(ushort4*)(out + ((size_t)b*N_ + q)*D_ + h*48 + md*16 + lc*4) = o;
    }
}

// ---------------- Depthwise 3x3 conv + GELU gate, 8 ch/thread ------------
__global__ __launch_bounds__(256) void dwconv_gate_bf16(
    const unsigned short* __restrict__ h, const float* __restrict__ dw_w,
    const float* __restrict__ dw_b, unsigned short* __restrict__ g) {
    __shared__ float wt_s[9][128];   // [tap][ch: 0..63 = h1, 64..127 = h2]
    __shared__ float bs_s[128];
    int tid = threadIdx.x;
    int cg0 = blockIdx.x * 64;
    int y   = blockIdx.y;
    int b   = blockIdx.z;
    for (int i = tid; i < 1152; i += 256) {
        int tap = i >> 7, cl = i & 127;
        int gch = (cl < 64) ? (cg0 + cl) : (HID_ + cg0 + (cl - 64));
        wt_s[tap][cl] = dw_w[(size_t)gch*9 + tap];
    }
    if (tid < 128) {
        int gch = (tid < 64) ? (cg0 + tid) : (HID_ + cg0 + (tid - 64));
        bs_s[tid] = dw_b[gch];
    }
    __syncthreads();
    int x  = tid >> 3;
    int co = (tid & 7) * 8;
    int c1 = cg0 + co;
    const unsigned short* hb = h + (size_t)b*N_*HID2_;
    float acc1[8], acc2[8];
    #pragma unroll
    for (int j=0;j<8;++j) { acc1[j] = bs_s[co+j]; acc2[j] = bs_s[64+co+j]; }
    #pragma unroll
    for (int ky=0; ky<3; ++ky) {
        int yy = y + ky - 1;
        if (yy < 0 || yy >= 32) continue;
        #pragma unroll
        for (int kx=0; kx<3; ++kx) {
            int xx = x + kx - 1;
            if (xx < 0 || xx >= 32) continue;
            const unsigned short* p = hb + (size_t)(yy*32+xx)*HID2_ + c1;
            bf16x8 d1 = *(const bf16x8*)p;
            bf16x8 d2 = *(const bf16x8*)(p + HID_);
            int t = ky*3 + kx;
            f32x4 w1a = *(const f32x4*)&wt_s[t][co];
            f32x4 w1b = *(const f32x4*)&wt_s[t][co+4];
            f32x4 w2a = *(const f32x4*)&wt_s[t][64+co];
            f32x4 w2b = *(const f32x4*)&wt_s[t][64+co+4];
            #pragma unroll
            for (int j=0;j<4;++j) {
                acc1[j]   += bf2f((unsigned short)d1[j])   * w1a[j];
                acc1[j+4] += bf2f((unsigned short)d1[j+4]) * w1b[j];
                acc2[j]   += bf2f((unsigned short)d2[j])   * w2a[j];
                acc2[j+4] += bf2f((unsigned short)d2[j+4]) * w2b[j];
            }
        }
    }
    bf16x8 o;
    #pragma unroll
    for (int j=0;j<8;++j) {
        float ge = 0.5f*acc1[j]*(1.0f + erff(acc1[j]*0.70710678118f));
        o[j] = (short)f2bf(ge * acc2[j]);
    }
    *(bf16x8*)(g + (size_t)(b*N_ + y*32 + x)*HID_ + c1) = o;
}

extern "C" void kernel_launch(void* const* d_in, const int* in_sizes, int n_in,
                              void* d_out, int out_size, void* d_ws, size_t ws_size,
                              hipStream_t stream) {
    const float* x_in   = (const float*)d_in[0];
    const float* qkv_w  = (const float*)d_in[1];
    const float* qkv_b  = (const float*)d_in[2];
    const float* proj_w = (const float*)d_in[3];
    const float* proj_b = (const float*)d_in[4];
    const float* ln1_g  = (const float*)d_in[5];
    const float* ln1_b  = (const float*)d_in[6];
    const float* ln2_g  = (const float*)d_in[7];
    const float* ln2_b  = (const float*)d_in[8];
    const float* pin_w  = (const float*)d_in[9];
    const float* pin_b  = (const float*)d_in[10];
    const float* dw_w   = (const float*)d_in[11];
    const float* dw_b   = (const float*)d_in[12];
    const float* pout_w = (const float*)d_in[13];
    const float* pout_b = (const float*)d_in[14];

    float* pX = (float*)d_out;                       // residual stream fp32
    unsigned short* wXn  = (unsigned short*)d_ws;                 // [M][384]
    unsigned short* wQKV = wXn  + (size_t)M_*D_;                  // [M][1152]
    unsigned short* wAO  = wQKV + (size_t)M_*3*D_;                // [M][384]
    unsigned short* wH   = wAO  + (size_t)M_*D_;                  // [M][1536]
    unsigned short* wG   = wH   + (size_t)M_*HID2_;               // [M][768]
    unsigned short* wWq  = wG   + (size_t)M_*HID_;                // weights bf16
    unsigned short* wWp  = wWq  + (size_t)2*3*D_*D_;
    unsigned short* wWi  = wWp  + (size_t)2*D_*D_;
    unsigned short* wWo  = wWi  + (size_t)2*HID2_*D_;

    int c1 = 2*3*D_*D_/4, c2 = 2*D_*D_/4, c3 = 2*HID2_*D_/4, c4 = 2*D_*HID_/4;
    int ctot = c1 + c2 + c3 + c4;
    cvt4_kernel<<<(ctot+255)/256, 256, 0, stream>>>(
        qkv_w, proj_w, pin_w, pout_w, c1, c2, c3, c4, wWq);

    hipMemcpyAsync(pX, x_in, sizeof(float)*(size_t)M_*D_,
                   hipMemcpyDeviceToDevice, stream);

    for (int l = 0; l < 2; ++l) {
        ln_kernel<<<M_/4, 256, 0, stream>>>(pX, ln1_g + l*D_, ln1_b + l*D_, wXn);
        gemm_bf16<0><<<dim3((3*D_)/128, M_/128), 256, 0, stream>>>(
            wXn, wWq + (size_t)l*3*D_*D_, qkv_b + (size_t)l*3*D_,
            nullptr, wQKV, M_, 3*D_, D_);
        attn_mfma<<<dim3(B_*NH_, N_/64), 256, 0, stream>>>(wQKV, wAO);
        gemm_bf16_s<1><<<dim3(D_/64, M_/64), 256, 0, stream>>>(
            wAO, wWp + (size_t)l*D_*D_, proj_b + (size_t)l*D_,
            pX, pX, M_, D_, D_);
        ln_kernel<<<M_/4, 256, 0, stream>>>(pX, ln2_g + l*D_, ln2_b + l*D_, wXn);
        gemm_bf16<0><<<dim3(HID2_/128, M_/128), 256, 0, stream>>>(
            wXn, wWi + (size_t)l*HID2_*D_, pin_b + (size_t)l*HID2_,
            nullptr, wH, M_, HID2_, D_);
        dwconv_gate_bf16<<<dim3(HID_/64, 32, B_), 256, 0, stream>>>(
            wH, dw_w + (size_t)l*HID2_*9, dw_b + (size_t)l*HID2_, wG);
        gemm_bf16_s<1><<<dim3(D_/64, M_/64), 256, 0, stream>>>(
            wG, wWo + (size_t)l*D_*HID_, pout_b + (size_t)l*D_,
            pX, pX, M_, D_, HID_);
    }
}